// Round 5
// baseline (1622.630 us; speedup 1.0000x reference)
//
#include <hip/hip_runtime.h>
#include <math.h>

static __device__ __forceinline__ float sigf(float x){ return 1.0f/(1.0f+__expf(-x)); }
static __device__ __forceinline__ float tanhf_fast(float x){
  float ax=fabsf(x); float e=__expf(-2.0f*ax); float t=(1.0f-e)/(1.0f+e); return copysignf(t,x);
}
// sum across quad (lanes 4k..4k+3); result valid in all 4 lanes (quad_perm is explicit)
static __device__ __forceinline__ float qsum(float v){
  v += __int_as_float(__builtin_amdgcn_mov_dpp(__float_as_int(v),0xB1,0xF,0xF,true)); // quad_perm xor1
  v += __int_as_float(__builtin_amdgcn_mov_dpp(__float_as_int(v),0x4E,0xF,0xF,true)); // quad_perm xor2
  return v;
}
// add value of lane^4 via ds_swizzle xor-mode (0x101F = xor 4, and 0x1F) — verified in r4 L2/L3
static __device__ __forceinline__ float rsum4(float v){
  return v + __int_as_float(__builtin_amdgcn_ds_swizzle(__float_as_int(v), 0x101F));
}
// cross-quad merge: lane keeps its own-unit quad-partial, receives the partner
// quad's partial OF THE SAME UNIT (partner sends its "other" accumulator).
static __device__ __forceinline__ float mrg(int usel, float a, float b){
  const float own = usel ? b : a;
  const float oth = usel ? a : b;
  return own + __int_as_float(__builtin_amdgcn_ds_swizzle(__float_as_int(oth), 0x101F));
}
static __device__ __forceinline__ float sel4(int c, float4 v){
  float r=v.x; r=(c==1)?v.y:r; r=(c==2)?v.z:r; r=(c==3)?v.w:r; return r;
}

// ---------------------------------------------------------------------------
// L1: I=1, H=100, 512 steps, 4 chains/block, 512 blocks (256 fwd + 256 bwd).
// 448 thr, 400 workers = 50 octets. Octet owns units (2p,2p+1); lane l owns
// cols 13l..13l+12 of the padded 104-col h (weights: 78 NAMED floats, no
// arrays -> no scratch). Reduce: qsum (quad DPP) + 12 merged xor-4 swizzles.
// Finalize constants live in LDS cst[100][8]. 1 barrier/step, hT dbuf.
// ---------------------------------------------------------------------------
__global__ __launch_bounds__(448, 4)
void gru_l1(const float* __restrict__ data,
            const float* __restrict__ wih_f, const float* __restrict__ whh_f,
            const float* __restrict__ bih_f, const float* __restrict__ bhh_f,
            const float* __restrict__ wih_b, const float* __restrict__ whh_b,
            const float* __restrict__ bih_b, const float* __restrict__ bhh_b,
            float* __restrict__ x1f, float* __restrict__ x1b,
            float* __restrict__ out)
{
  const int dir = (int)(blockIdx.x >> 8);
  const int blk = (int)(blockIdx.x & 255);
  const int t   = (int)threadIdx.x;
  const float* __restrict__ wih = dir ? wih_b : wih_f;
  const float* __restrict__ whh = dir ? whh_b : whh_f;
  const float* __restrict__ bih = dir ? bih_b : bih_f;
  const float* __restrict__ bhh = dir ? bhh_b : bhh_f;
  float* __restrict__ x1 = dir ? x1b : x1f;
  const int obase = dir ? 200 : 0;
  const int b0 = blk * 4;

  __shared__ __align__(16) float xs[512][4];
  __shared__ __align__(16) float hT[2][104][4];   // rows 100-103 stay zero
  __shared__ __align__(16) float cst[100][8];     // wxr,wxz,wxn,bcr | bcz,bxn,bhn,0

  for (int k = t; k < 512; k += 448){
    const int sidx = dir ? (511 - k) : k;
    xs[k][0] = data[(size_t)(b0+0)*512 + sidx];
    xs[k][1] = data[(size_t)(b0+1)*512 + sidx];
    xs[k][2] = data[(size_t)(b0+2)*512 + sidx];
    xs[k][3] = data[(size_t)(b0+3)*512 + sidx];
  }
  for (int i = t; i < 208; i += 448){
    const int bi = (i >= 104) ? 1 : 0;
    *(float4*)&hT[bi][i - bi*104][0] = make_float4(0.f,0.f,0.f,0.f);
  }
  if (t < 100){
    const float wxr=wih[t], wxz=wih[t+100], wxn=wih[t+200];
    const float bcr=bih[t]+bhh[t], bcz=bih[t+100]+bhh[t+100];
    const float bxn=bih[t+200], bhn=bhh[t+200];
    *(float4*)&cst[t][0] = make_float4(wxr,wxz,wxn,bcr);
    *(float4*)&cst[t][4] = make_float4(bcz,bxn,bhn,0.f);
  }

  const int oct = ((t < 400) ? t : 399) >> 3;   // 0..49
  const int l   = t & 7;
  const int u0  = oct * 2;
  const int cb  = 13 * l;                       // 0..91
  const float* rowRA = whh + (size_t)(u0      )*100;
  const float* rowZA = whh + (size_t)(u0 + 100)*100;
  const float* rowNA = whh + (size_t)(u0 + 200)*100;
  // guard cols >=100 (only lane 7): clamp index, zero via multiply (no OOB)
  #define GW(ROW,K) ( (ROW)[ ((cb+(K)) < 100) ? (cb+(K)) : 0 ] * (((cb+(K)) < 100) ? 1.0f : 0.0f) )
  float4 RA0 = make_float4(GW(rowRA,0),GW(rowRA,1),GW(rowRA,2),GW(rowRA,3));
  float4 RA1 = make_float4(GW(rowRA,4),GW(rowRA,5),GW(rowRA,6),GW(rowRA,7));
  float4 RA2 = make_float4(GW(rowRA,8),GW(rowRA,9),GW(rowRA,10),GW(rowRA,11));
  float  RA3 = GW(rowRA,12);
  float4 ZA0 = make_float4(GW(rowZA,0),GW(rowZA,1),GW(rowZA,2),GW(rowZA,3));
  float4 ZA1 = make_float4(GW(rowZA,4),GW(rowZA,5),GW(rowZA,6),GW(rowZA,7));
  float4 ZA2 = make_float4(GW(rowZA,8),GW(rowZA,9),GW(rowZA,10),GW(rowZA,11));
  float  ZA3 = GW(rowZA,12);
  float4 NA0 = make_float4(GW(rowNA,0),GW(rowNA,1),GW(rowNA,2),GW(rowNA,3));
  float4 NA1 = make_float4(GW(rowNA,4),GW(rowNA,5),GW(rowNA,6),GW(rowNA,7));
  float4 NA2 = make_float4(GW(rowNA,8),GW(rowNA,9),GW(rowNA,10),GW(rowNA,11));
  float  NA3 = GW(rowNA,12);
  const float* rowRB = rowRA + 100;
  const float* rowZB = rowZA + 100;
  const float* rowNB = rowNA + 100;
  float4 RB0 = make_float4(GW(rowRB,0),GW(rowRB,1),GW(rowRB,2),GW(rowRB,3));
  float4 RB1 = make_float4(GW(rowRB,4),GW(rowRB,5),GW(rowRB,6),GW(rowRB,7));
  float4 RB2 = make_float4(GW(rowRB,8),GW(rowRB,9),GW(rowRB,10),GW(rowRB,11));
  float  RB3 = GW(rowRB,12);
  float4 ZB0 = make_float4(GW(rowZB,0),GW(rowZB,1),GW(rowZB,2),GW(rowZB,3));
  float4 ZB1 = make_float4(GW(rowZB,4),GW(rowZB,5),GW(rowZB,6),GW(rowZB,7));
  float4 ZB2 = make_float4(GW(rowZB,8),GW(rowZB,9),GW(rowZB,10),GW(rowZB,11));
  float  ZB3 = GW(rowZB,12);
  float4 NB0 = make_float4(GW(rowNB,0),GW(rowNB,1),GW(rowNB,2),GW(rowNB,3));
  float4 NB1 = make_float4(GW(rowNB,4),GW(rowNB,5),GW(rowNB,6),GW(rowNB,7));
  float4 NB2 = make_float4(GW(rowNB,8),GW(rowNB,9),GW(rowNB,10),GW(rowNB,11));
  float  NB3 = GW(rowNB,12);
  #undef GW
  __syncthreads();

  #pragma unroll 1
  for (int s = 0; s < 512; ++s){
    const int cur = s & 1, nxt = cur ^ 1;
    if (t < 400){
      const float* hb = &hT[cur][cb][0];
      float arA0=0,arA1=0,arA2=0,arA3=0, azA0=0,azA1=0,azA2=0,azA3=0, anA0=0,anA1=0,anA2=0,anA3=0;
      float arB0=0,arB1=0,arB2=0,arB3=0, azB0=0,azB1=0,azB2=0,azB3=0, anB0=0,anB1=0,anB2=0,anB3=0;
      #define AC6(H, wra,wza,wna,wrb,wzb,wnb) { \
        arA0=fmaf(wra,H.x,arA0); arA1=fmaf(wra,H.y,arA1); arA2=fmaf(wra,H.z,arA2); arA3=fmaf(wra,H.w,arA3); \
        azA0=fmaf(wza,H.x,azA0); azA1=fmaf(wza,H.y,azA1); azA2=fmaf(wza,H.z,azA2); azA3=fmaf(wza,H.w,azA3); \
        anA0=fmaf(wna,H.x,anA0); anA1=fmaf(wna,H.y,anA1); anA2=fmaf(wna,H.z,anA2); anA3=fmaf(wna,H.w,anA3); \
        arB0=fmaf(wrb,H.x,arB0); arB1=fmaf(wrb,H.y,arB1); arB2=fmaf(wrb,H.z,arB2); arB3=fmaf(wrb,H.w,arB3); \
        azB0=fmaf(wzb,H.x,azB0); azB1=fmaf(wzb,H.y,azB1); azB2=fmaf(wzb,H.z,azB2); azB3=fmaf(wzb,H.w,azB3); \
        anB0=fmaf(wnb,H.x,anB0); anB1=fmaf(wnb,H.y,anB1); anB2=fmaf(wnb,H.z,anB2); anB3=fmaf(wnb,H.w,anB3); }
      { float4 h;
        h=*(const float4*)(hb+ 0); AC6(h, RA0.x,ZA0.x,NA0.x, RB0.x,ZB0.x,NB0.x)
        h=*(const float4*)(hb+ 4); AC6(h, RA0.y,ZA0.y,NA0.y, RB0.y,ZB0.y,NB0.y)
        h=*(const float4*)(hb+ 8); AC6(h, RA0.z,ZA0.z,NA0.z, RB0.z,ZB0.z,NB0.z)
        h=*(const float4*)(hb+12); AC6(h, RA0.w,ZA0.w,NA0.w, RB0.w,ZB0.w,NB0.w)
        h=*(const float4*)(hb+16); AC6(h, RA1.x,ZA1.x,NA1.x, RB1.x,ZB1.x,NB1.x)
        h=*(const float4*)(hb+20); AC6(h, RA1.y,ZA1.y,NA1.y, RB1.y,ZB1.y,NB1.y)
        h=*(const float4*)(hb+24); AC6(h, RA1.z,ZA1.z,NA1.z, RB1.z,ZB1.z,NB1.z)
        h=*(const float4*)(hb+28); AC6(h, RA1.w,ZA1.w,NA1.w, RB1.w,ZB1.w,NB1.w)
        h=*(const float4*)(hb+32); AC6(h, RA2.x,ZA2.x,NA2.x, RB2.x,ZB2.x,NB2.x)
        h=*(const float4*)(hb+36); AC6(h, RA2.y,ZA2.y,NA2.y, RB2.y,ZB2.y,NB2.y)
        h=*(const float4*)(hb+40); AC6(h, RA2.z,ZA2.z,NA2.z, RB2.z,ZB2.z,NB2.z)
        h=*(const float4*)(hb+44); AC6(h, RA2.w,ZA2.w,NA2.w, RB2.w,ZB2.w,NB2.w)
        h=*(const float4*)(hb+48); AC6(h, RA3,  ZA3,  NA3,   RB3,  ZB3,  NB3  )
      }
      #undef AC6
      arA0=qsum(arA0); arA1=qsum(arA1); arA2=qsum(arA2); arA3=qsum(arA3);
      azA0=qsum(azA0); azA1=qsum(azA1); azA2=qsum(azA2); azA3=qsum(azA3);
      anA0=qsum(anA0); anA1=qsum(anA1); anA2=qsum(anA2); anA3=qsum(anA3);
      arB0=qsum(arB0); arB1=qsum(arB1); arB2=qsum(arB2); arB3=qsum(arB3);
      azB0=qsum(azB0); azB1=qsum(azB1); azB2=qsum(azB2); azB3=qsum(azB3);
      anB0=qsum(anB0); anB1=qsum(anB1); anB2=qsum(anB2); anB3=qsum(anB3);
      const int usel = (l >> 2) & 1;
      const float fr0=mrg(usel,arA0,arB0), fr1=mrg(usel,arA1,arB1), fr2=mrg(usel,arA2,arB2), fr3=mrg(usel,arA3,arB3);
      const float fz0=mrg(usel,azA0,azB0), fz1=mrg(usel,azA1,azB1), fz2=mrg(usel,azA2,azB2), fz3=mrg(usel,azA3,azB3);
      const float fn0=mrg(usel,anA0,anB0), fn1=mrg(usel,anA1,anB1), fn2=mrg(usel,anA2,anB2), fn3=mrg(usel,anA3,anB3);
      const int cf = l & 3;
      const int uf = u0 + usel;
      const float Ar = sel4(cf, make_float4(fr0,fr1,fr2,fr3));
      const float Az = sel4(cf, make_float4(fz0,fz1,fz2,fz3));
      const float An = sel4(cf, make_float4(fn0,fn1,fn2,fn3));
      const float xc = xs[s][cf];
      const float ho = hT[cur][uf][cf];
      const float4 c0 = *(const float4*)&cst[uf][0];  // wxr,wxz,wxn,bcr
      const float4 c1 = *(const float4*)&cst[uf][4];  // bcz,bxn,bhn,0
      const float r = sigf(fmaf(c0.x, xc, c0.w) + Ar);
      const float z = sigf(fmaf(c0.y, xc, c1.x) + Az);
      const float n = tanhf_fast(fmaf(c0.z, xc, c1.y) + r*(An + c1.z));
      const float hnew = n + z*(ho - n);
      hT[nxt][uf][cf] = hnew;
      if ((s & 3) == 3) x1[(((size_t)(s>>2)*256 + blk)*100 + uf)*4 + cf] = hnew;
      if (s == 511)     out[(size_t)(b0 + cf)*400 + obase + uf] = hnew;
    }
    __syncthreads();
  }
}

// ---------------------------------------------------------------------------
// L2: I=100, H=50, 128 steps, lane-3 chains, 4 chains/block, 512 blocks.
// (unchanged from round 4 — verified correct)
// ---------------------------------------------------------------------------
__global__ __launch_bounds__(512, 4)
void gru_l2(const float* __restrict__ x1f, const float* __restrict__ x1b,
            const float* __restrict__ wih_f, const float* __restrict__ whh_f,
            const float* __restrict__ bih_f, const float* __restrict__ bhh_f,
            const float* __restrict__ wih_b, const float* __restrict__ whh_b,
            const float* __restrict__ bih_b, const float* __restrict__ bhh_b,
            float* __restrict__ x2f, float* __restrict__ x2b,
            float* __restrict__ out)
{
  const int dir = (int)(blockIdx.x >> 8);
  const int blk = (int)(blockIdx.x & 255);
  const int t   = (int)threadIdx.x;
  const float* __restrict__ wih = dir ? wih_b : wih_f;
  const float* __restrict__ whh = dir ? whh_b : whh_f;
  const float* __restrict__ bih = dir ? bih_b : bih_f;
  const float* __restrict__ bhh = dir ? bhh_b : bhh_f;
  const float* __restrict__ x1 = dir ? x1b : x1f;
  float* __restrict__ x2 = dir ? x2b : x2f;
  const int obase = dir ? 300 : 100;
  const int b0 = blk * 4;

  __shared__ __align__(16) float xh[2][152][4];

  const int oct = t >> 3;
  const int u   = (oct > 49) ? 49 : oct;
  const int l   = t & 7;
  const int cb  = 19 * l;           // combined col base (0..133)
  float4 W0,W1,W2,W3,W4,W5,W6,W7,W8,W9,W10,W11,W12,W13,W14,W15,W16,W17,W18;
  #define L2LW(J, V) { const int g = cb + (J); \
    const float wr_ = (g<100) ? wih[(size_t)(u     )*100+g] : ((g<150)? whh[(size_t)(u     )*50+g-100] : 0.f); \
    const float wz_ = (g<100) ? wih[(size_t)(u + 50)*100+g] : ((g<150)? whh[(size_t)(u + 50)*50+g-100] : 0.f); \
    const float wx_ = (g<100) ? wih[(size_t)(u +100)*100+g] : 0.f; \
    const float wh_ = (g>=100 && g<150) ? whh[(size_t)(u +100)*50+g-100] : 0.f; \
    V = make_float4(wr_, wz_, wx_, wh_); }
  L2LW(0,W0)  L2LW(1,W1)  L2LW(2,W2)  L2LW(3,W3)  L2LW(4,W4)  L2LW(5,W5)  L2LW(6,W6)
  L2LW(7,W7)  L2LW(8,W8)  L2LW(9,W9)  L2LW(10,W10) L2LW(11,W11) L2LW(12,W12) L2LW(13,W13)
  L2LW(14,W14) L2LW(15,W15) L2LW(16,W16) L2LW(17,W17) L2LW(18,W18)
  #undef L2LW
  const float bcr = bih[u] + bhh[u];
  const float bcz = bih[u+50] + bhh[u+50];
  const float bxn = bih[u+100];
  const float bhn = bhh[u+100];

  for (int i = t; i < 104; i += 512){            // zero h rows + pads, both buffers
    const int bi = (i >= 52) ? 1 : 0;
    const int row = 100 + (i - bi*52);
    *(float4*)&xh[bi][row][0] = make_float4(0.f,0.f,0.f,0.f);
  }
  if (t < 100)                                    // stage x for step 0
    *(float4*)&xh[0][t][0] = *(const float4*)(x1 + (((size_t)0*256 + blk)*100 + t)*4);
  __syncthreads();

  #pragma unroll 1
  for (int s = 0; s < 128; ++s){
    const int cur = s & 1, nxt = cur ^ 1;
    if (t < 400){
      const float* hb = &xh[cur][cb][0];
      float ar0=0,ar1=0,ar2=0,ar3=0, az0=0,az1=0,az2=0,az3=0;
      float ax0=0,ax1=0,ax2=0,ax3=0, ah0=0,ah1=0,ah2=0,ah3=0;
      #define L2C(J, WV) { const float4 h4 = *(const float4*)(hb + 4*(J)); \
        ar0=fmaf(WV.x,h4.x,ar0); ar1=fmaf(WV.x,h4.y,ar1); ar2=fmaf(WV.x,h4.z,ar2); ar3=fmaf(WV.x,h4.w,ar3); \
        az0=fmaf(WV.y,h4.x,az0); az1=fmaf(WV.y,h4.y,az1); az2=fmaf(WV.y,h4.z,az2); az3=fmaf(WV.y,h4.w,az3); \
        ax0=fmaf(WV.z,h4.x,ax0); ax1=fmaf(WV.z,h4.y,ax1); ax2=fmaf(WV.z,h4.z,ax2); ax3=fmaf(WV.z,h4.w,ax3); \
        ah0=fmaf(WV.w,h4.x,ah0); ah1=fmaf(WV.w,h4.y,ah1); ah2=fmaf(WV.w,h4.z,ah2); ah3=fmaf(WV.w,h4.w,ah3); }
      L2C(0,W0)  L2C(1,W1)  L2C(2,W2)  L2C(3,W3)  L2C(4,W4)  L2C(5,W5)  L2C(6,W6)
      L2C(7,W7)  L2C(8,W8)  L2C(9,W9)  L2C(10,W10) L2C(11,W11) L2C(12,W12) L2C(13,W13)
      L2C(14,W14) L2C(15,W15) L2C(16,W16) L2C(17,W17) L2C(18,W18)
      #undef L2C
      ar0=qsum(ar0); ar1=qsum(ar1); ar2=qsum(ar2); ar3=qsum(ar3);
      az0=qsum(az0); az1=qsum(az1); az2=qsum(az2); az3=qsum(az3);
      ax0=qsum(ax0); ax1=qsum(ax1); ax2=qsum(ax2); ax3=qsum(ax3);
      ah0=qsum(ah0); ah1=qsum(ah1); ah2=qsum(ah2); ah3=qsum(ah3);
      ar0=rsum4(ar0); ar1=rsum4(ar1); ar2=rsum4(ar2); ar3=rsum4(ar3);
      az0=rsum4(az0); az1=rsum4(az1); az2=rsum4(az2); az3=rsum4(az3);
      ax0=rsum4(ax0); ax1=rsum4(ax1); ax2=rsum4(ax2); ax3=rsum4(ax3);
      ah0=rsum4(ah0); ah1=rsum4(ah1); ah2=rsum4(ah2); ah3=rsum4(ah3);
      if (l < 4){
        const float Ar = sel4(l, make_float4(ar0,ar1,ar2,ar3));
        const float Az = sel4(l, make_float4(az0,az1,az2,az3));
        const float Ax = sel4(l, make_float4(ax0,ax1,ax2,ax3));
        const float Ah = sel4(l, make_float4(ah0,ah1,ah2,ah3));
        const float ho = xh[cur][100+u][l];
        const float r = sigf(Ar + bcr);
        const float z = sigf(Az + bcz);
        const float n = tanhf_fast(Ax + bxn + r*(Ah + bhn));
        const float hnew = n + z*(ho - n);
        xh[nxt][100+u][l] = hnew;
        if ((s & 3) == 3) x2[(((size_t)(s>>2)*256 + blk)*50 + u)*4 + l] = hnew;
        if (s == 127)     out[(size_t)(b0 + l)*400 + obase + u] = hnew;
      }
    } else if (t < 500){
      if (s + 1 < 128){
        const int j = t - 400;
        *(float4*)&xh[nxt][j][0] = *(const float4*)(x1 + (((size_t)(s+1)*256 + blk)*100 + j)*4);
      }
    }
    __syncthreads();
  }
}

// ---------------------------------------------------------------------------
// L3: I=50, H=50, 32 steps, lane-15 chains. (unchanged from round 4)
// ---------------------------------------------------------------------------
__global__ __launch_bounds__(512, 4)
void gru_l3(const float* __restrict__ x2f, const float* __restrict__ x2b,
            const float* __restrict__ wih_f, const float* __restrict__ whh_f,
            const float* __restrict__ bih_f, const float* __restrict__ bhh_f,
            const float* __restrict__ wih_b, const float* __restrict__ whh_b,
            const float* __restrict__ bih_b, const float* __restrict__ bhh_b,
            float* __restrict__ out)
{
  const int dir = (int)(blockIdx.x >> 8);
  const int blk = (int)(blockIdx.x & 255);
  const int t   = (int)threadIdx.x;
  const float* __restrict__ wih = dir ? wih_b : wih_f;
  const float* __restrict__ whh = dir ? whh_b : whh_f;
  const float* __restrict__ bih = dir ? bih_b : bih_f;
  const float* __restrict__ bhh = dir ? bhh_b : bhh_f;
  const float* __restrict__ x2 = dir ? x2b : x2f;
  const int obase = dir ? 350 : 150;
  const int b0 = blk * 4;

  __shared__ __align__(16) float xh[2][104][4];

  const int oct = t >> 3;
  const int u   = (oct > 49) ? 49 : oct;
  const int l   = t & 7;
  const int cb  = 13 * l;           // 0..91
  float4 W0,W1,W2,W3,W4,W5,W6,W7,W8,W9,W10,W11,W12;
  #define L3LW(J, V) { const int g = cb + (J); \
    const float wr_ = (g<50) ? wih[(size_t)(u     )*50+g] : ((g<100)? whh[(size_t)(u     )*50+g-50] : 0.f); \
    const float wz_ = (g<50) ? wih[(size_t)(u + 50)*50+g] : ((g<100)? whh[(size_t)(u + 50)*50+g-50] : 0.f); \
    const float wx_ = (g<50) ? wih[(size_t)(u +100)*50+g] : 0.f; \
    const float wh_ = (g>=50 && g<100) ? whh[(size_t)(u +100)*50+g-50] : 0.f; \
    V = make_float4(wr_, wz_, wx_, wh_); }
  L3LW(0,W0) L3LW(1,W1) L3LW(2,W2) L3LW(3,W3) L3LW(4,W4) L3LW(5,W5) L3LW(6,W6)
  L3LW(7,W7) L3LW(8,W8) L3LW(9,W9) L3LW(10,W10) L3LW(11,W11) L3LW(12,W12)
  #undef L3LW
  const float bcr = bih[u] + bhh[u];
  const float bcz = bih[u+50] + bhh[u+50];
  const float bxn = bih[u+100];
  const float bhn = bhh[u+100];

  for (int i = t; i < 108; i += 512){            // zero h rows + pads, both buffers
    const int bi = (i >= 54) ? 1 : 0;
    const int row = 50 + (i - bi*54);
    *(float4*)&xh[bi][row][0] = make_float4(0.f,0.f,0.f,0.f);
  }
  if (t < 50)
    *(float4*)&xh[0][t][0] = *(const float4*)(x2 + (((size_t)0*256 + blk)*50 + t)*4);
  __syncthreads();

  #pragma unroll 1
  for (int s = 0; s < 32; ++s){
    const int cur = s & 1, nxt = cur ^ 1;
    if (t < 400){
      const float* hb = &xh[cur][cb][0];
      float ar0=0,ar1=0,ar2=0,ar3=0, az0=0,az1=0,az2=0,az3=0;
      float ax0=0,ax1=0,ax2=0,ax3=0, ah0=0,ah1=0,ah2=0,ah3=0;
      #define L3C(J, WV) { const float4 h4 = *(const float4*)(hb + 4*(J)); \
        ar0=fmaf(WV.x,h4.x,ar0); ar1=fmaf(WV.x,h4.y,ar1); ar2=fmaf(WV.x,h4.z,ar2); ar3=fmaf(WV.x,h4.w,ar3); \
        az0=fmaf(WV.y,h4.x,az0); az1=fmaf(WV.y,h4.y,az1); az2=fmaf(WV.y,h4.z,az2); az3=fmaf(WV.y,h4.w,az3); \
        ax0=fmaf(WV.z,h4.x,ax0); ax1=fmaf(WV.z,h4.y,ax1); ax2=fmaf(WV.z,h4.z,ax2); ax3=fmaf(WV.z,h4.w,ax3); \
        ah0=fmaf(WV.w,h4.x,ah0); ah1=fmaf(WV.w,h4.y,ah1); ah2=fmaf(WV.w,h4.z,ah2); ah3=fmaf(WV.w,h4.w,ah3); }
      L3C(0,W0) L3C(1,W1) L3C(2,W2) L3C(3,W3) L3C(4,W4) L3C(5,W5) L3C(6,W6)
      L3C(7,W7) L3C(8,W8) L3C(9,W9) L3C(10,W10) L3C(11,W11) L3C(12,W12)
      #undef L3C
      ar0=qsum(ar0); ar1=qsum(ar1); ar2=qsum(ar2); ar3=qsum(ar3);
      az0=qsum(az0); az1=qsum(az1); az2=qsum(az2); az3=qsum(az3);
      ax0=qsum(ax0); ax1=qsum(ax1); ax2=qsum(ax2); ax3=qsum(ax3);
      ah0=qsum(ah0); ah1=qsum(ah1); ah2=qsum(ah2); ah3=qsum(ah3);
      ar0=rsum4(ar0); ar1=rsum4(ar1); ar2=rsum4(ar2); ar3=rsum4(ar3);
      az0=rsum4(az0); az1=rsum4(az1); az2=rsum4(az2); az3=rsum4(az3);
      ax0=rsum4(ax0); ax1=rsum4(ax1); ax2=rsum4(ax2); ax3=rsum4(ax3);
      ah0=rsum4(ah0); ah1=rsum4(ah1); ah2=rsum4(ah2); ah3=rsum4(ah3);
      if (l < 4){
        const float Ar = sel4(l, make_float4(ar0,ar1,ar2,ar3));
        const float Az = sel4(l, make_float4(az0,az1,az2,az3));
        const float Ax = sel4(l, make_float4(ax0,ax1,ax2,ax3));
        const float Ah = sel4(l, make_float4(ah0,ah1,ah2,ah3));
        const float ho = xh[cur][50+u][l];
        const float r = sigf(Ar + bcr);
        const float z = sigf(Az + bcz);
        const float n = tanhf_fast(Ax + bxn + r*(Ah + bhn));
        const float hnew = n + z*(ho - n);
        xh[nxt][50+u][l] = hnew;
        if (s == 31) out[(size_t)(b0 + l)*400 + obase + u] = hnew;
      }
    } else if (t < 450){
      if (s + 1 < 32){
        const int j = t - 400;
        *(float4*)&xh[nxt][j][0] = *(const float4*)(x2 + (((size_t)(s+1)*256 + blk)*50 + j)*4);
      }
    }
    __syncthreads();
  }
}

extern "C" void kernel_launch(void* const* d_in, const int* in_sizes, int n_in,
                              void* d_out, int out_size, void* d_ws, size_t ws_size,
                              hipStream_t stream)
{
  const float* data   = (const float*)d_in[0];
  const float* f1_wih = (const float*)d_in[1];
  const float* f1_whh = (const float*)d_in[2];
  const float* f1_bih = (const float*)d_in[3];
  const float* f1_bhh = (const float*)d_in[4];
  const float* f2_wih = (const float*)d_in[5];
  const float* f2_whh = (const float*)d_in[6];
  const float* f2_bih = (const float*)d_in[7];
  const float* f2_bhh = (const float*)d_in[8];
  const float* f3_wih = (const float*)d_in[9];
  const float* f3_whh = (const float*)d_in[10];
  const float* f3_bih = (const float*)d_in[11];
  const float* f3_bhh = (const float*)d_in[12];
  const float* b1_wih = (const float*)d_in[13];
  const float* b1_whh = (const float*)d_in[14];
  const float* b1_bih = (const float*)d_in[15];
  const float* b1_bhh = (const float*)d_in[16];
  const float* b2_wih = (const float*)d_in[17];
  const float* b2_whh = (const float*)d_in[18];
  const float* b2_bih = (const float*)d_in[19];
  const float* b2_bhh = (const float*)d_in[20];
  const float* b3_wih = (const float*)d_in[21];
  const float* b3_whh = (const float*)d_in[22];
  const float* b3_bih = (const float*)d_in[23];
  const float* b3_bhh = (const float*)d_in[24];
  float* out = (float*)d_out;

  const size_t X1N = (size_t)128 * 256 * 100 * 4;  // [cs][blk][unit][chain]
  const size_t X2N = (size_t)32 * 256 * 50 * 4;    // [k2][blk][unit][chain]
  if (ws_size < (2 * X1N + 2 * X2N) * sizeof(float)) return;
  float* wsf = (float*)d_ws;
  float* x1f = wsf;
  float* x1b = wsf + X1N;
  float* x2f = wsf + 2 * X1N;
  float* x2b = wsf + 2 * X1N + X2N;

  gru_l1<<<dim3(512), dim3(448), 0, stream>>>(
      data, f1_wih, f1_whh, f1_bih, f1_bhh,
      b1_wih, b1_whh, b1_bih, b1_bhh, x1f, x1b, out);
  gru_l2<<<dim3(512), dim3(512), 0, stream>>>(
      x1f, x1b, f2_wih, f2_whh, f2_bih, f2_bhh,
      b2_wih, b2_whh, b2_bih, b2_bhh, x2f, x2b, out);
  gru_l3<<<dim3(512), dim3(512), 0, stream>>>(
      x2f, x2b, f3_wih, f3_whh, f3_bih, f3_bhh,
      b3_wih, b3_whh, b3_bih, b3_bhh, out);
}

// Round 6
// 1330.403 us; speedup vs baseline: 1.2197x; 1.2197x over previous
//
#include <hip/hip_runtime.h>
#include <math.h>

typedef short  s16x8 __attribute__((ext_vector_type(8)));   // 8 bf16 bit-patterns (4 VGPRs)
typedef float  f32x4 __attribute__((ext_vector_type(4)));

static __device__ __forceinline__ float sigf(float x){ return 1.0f/(1.0f+__expf(-x)); }
static __device__ __forceinline__ float tanhf_fast(float x){
  float ax=fabsf(x); float e=__expf(-2.0f*ax); float t=(1.0f-e)/(1.0f+e); return copysignf(t,x);
}
static __device__ __forceinline__ unsigned short f2bf(float x){  // RNE f32->bf16 bits
  unsigned int u = __float_as_uint(x);
  unsigned int r = (u + 0x7FFFu + ((u >> 16) & 1u)) >> 16;
  return (unsigned short)r;
}
static __device__ __forceinline__ float bf2f(unsigned short b){
  return __uint_as_float(((unsigned int)b) << 16);
}
// quad/octet reduce helpers (verified r4) — used by L2/L3
static __device__ __forceinline__ float qsum(float v){
  v += __int_as_float(__builtin_amdgcn_mov_dpp(__float_as_int(v),0xB1,0xF,0xF,true));
  v += __int_as_float(__builtin_amdgcn_mov_dpp(__float_as_int(v),0x4E,0xF,0xF,true));
  return v;
}
static __device__ __forceinline__ float rsum4(float v){
  return v + __int_as_float(__builtin_amdgcn_ds_swizzle(__float_as_int(v), 0x101F));
}
static __device__ __forceinline__ float sel4(int c, float4 v){
  float r=v.x; r=(c==1)?v.y:r; r=(c==2)?v.z:r; r=(c==3)?v.w:r; return r;
}

// load one A-fragment pair (hi/lo split) of the weight tile.
// A layout for mfma_f32_16x16x32_bf16: lane l holds A[m = l&15][k = (l>>4)*8 + j], j=0..7.
static __device__ __forceinline__ void load_afrag(const float* __restrict__ whh,
                                                  int tile, int l, int kc,
                                                  s16x8& hi, s16x8& lo){
  const int g   = tile >> 3;                 // gate 0..2
  const int row = (tile & 7)*16 + (l & 15);  // 0..127 within gate (pad >=100 zero)
  const int kb  = kc*32 + (l >> 4)*8;        // 0..120
  #pragma unroll
  for (int j = 0; j < 8; ++j){
    const int k = kb + j;
    const float wv = (row < 100 && k < 100) ? whh[(size_t)(g*100 + row)*100 + k] : 0.0f;
    const unsigned short hb = f2bf(wv);
    hi[j] = (short)hb;
    lo[j] = (short)f2bf(wv - bf2f(hb));
  }
}

// ---------------------------------------------------------------------------
// L1 (MFMA): I=1, H=100, 512 steps, 16 chains/block, 128 blocks (64 fwd + 64
// bwd), 512 threads = 8 waves. Per step: D = Wp(384x128,bf16-split) x
// h(128x16): 24 row-tiles (3 gates x 8), wave w owns tiles 3w..3w+2; K = 4
// chunks of 32; 3-term bf16 split => 36 MFMA/wave/step. Weights live in VGPR
// A-frags all steps. h kept in LDS [chain][k] bf16 hi/lo (dbuf) + f32 copy.
// Pre-activations go through LDS Sg[gate][chain][row]; 400 lanes finalize
// 4 GRU cells each. 2 barriers/step.
// ---------------------------------------------------------------------------
__global__ __launch_bounds__(512, 2)
void gru_l1(const float* __restrict__ data,
            const float* __restrict__ wih_f, const float* __restrict__ whh_f,
            const float* __restrict__ bih_f, const float* __restrict__ bhh_f,
            const float* __restrict__ wih_b, const float* __restrict__ whh_b,
            const float* __restrict__ bih_b, const float* __restrict__ bhh_b,
            float* __restrict__ x1f, float* __restrict__ x1b,
            float* __restrict__ out)
{
  const int dir   = (int)(blockIdx.x >> 6);
  const int blk16 = (int)(blockIdx.x & 63);
  const int t     = (int)threadIdx.x;
  const float* __restrict__ wih = dir ? wih_b : wih_f;
  const float* __restrict__ whh = dir ? whh_b : whh_f;
  const float* __restrict__ bih = dir ? bih_b : bih_f;
  const float* __restrict__ bhh = dir ? bhh_b : bhh_f;
  float* __restrict__ x1 = dir ? x1b : x1f;
  const int obase = dir ? 200 : 0;
  const int b0 = blk16 * 16;

  __shared__ __align__(16) unsigned short hBhi[2][16][136]; // [buf][chain][k] bf16 bits
  __shared__ __align__(16) unsigned short hBlo[2][16][136];
  __shared__ __align__(16) float Sg[3][16][108];            // [gate][chain][row] pre-acts
  __shared__ __align__(16) float hF[16][108];               // f32 h, [chain][unit]

  // zero hB (incl. k-pad region 100..135 — A pad is 0 so B pad must not be NaN)
  { unsigned short* ph = (unsigned short*)hBhi;
    unsigned short* pl = (unsigned short*)hBlo;
    for (int i = t; i < 2*16*136; i += 512){ ph[i] = 0; pl[i] = 0; }
    float* pf = (float*)hF;
    for (int i = t; i < 16*108; i += 512) pf[i] = 0.f; }

  const int l = t & 63;
  const int W = t >> 6;   // wave 0..7

  // A-fragments: 3 tiles x 4 k-chunks x (hi,lo) = 24 named frags (96 VGPRs)
  s16x8 AH00,AH01,AH02,AH03, AH10,AH11,AH12,AH13, AH20,AH21,AH22,AH23;
  s16x8 AL00,AL01,AL02,AL03, AL10,AL11,AL12,AL13, AL20,AL21,AL22,AL23;
  #define LDA(I,KC) load_afrag(whh, 3*W + (I), l, (KC), AH##I##KC, AL##I##KC);
  LDA(0,0) LDA(0,1) LDA(0,2) LDA(0,3)
  LDA(1,0) LDA(1,1) LDA(1,2) LDA(1,3)
  LDA(2,0) LDA(2,1) LDA(2,2) LDA(2,3)
  #undef LDA

  // finalize constants in registers (lane t<400 owns units ub*4..+3, chain t&15)
  const int ubc = ((t < 400) ? t : 399) >> 4;   // 0..24
  const int bcF = t & 15;
  const f32x4 wxr4 = *(const f32x4*)&wih[ubc*4];
  const f32x4 wxz4 = *(const f32x4*)&wih[100 + ubc*4];
  const f32x4 wxn4 = *(const f32x4*)&wih[200 + ubc*4];
  const f32x4 bir  = *(const f32x4*)&bih[ubc*4];
  const f32x4 bhr  = *(const f32x4*)&bhh[ubc*4];
  const f32x4 biz  = *(const f32x4*)&bih[100 + ubc*4];
  const f32x4 bhz  = *(const f32x4*)&bhh[100 + ubc*4];
  const f32x4 bxn4 = *(const f32x4*)&bih[200 + ubc*4];
  const f32x4 bhn4 = *(const f32x4*)&bhh[200 + ubc*4];
  const f32x4 bcr4 = bir + bhr;
  const f32x4 bcz4 = biz + bhz;

  __syncthreads();

  const int bn = l & 15;        // B-frag: n (chain)
  const int bg = (l >> 4)*8;    // B-frag: k offset within chunk

  #pragma unroll 1
  for (int s = 0; s < 512; ++s){
    const int cur = s & 1, nxt = cur ^ 1;

    // ---- phase 1: MFMA (all 8 waves) ----
    const s16x8 BH0 = *(const s16x8*)&hBhi[cur][bn][ 0 + bg];
    const s16x8 BL0 = *(const s16x8*)&hBlo[cur][bn][ 0 + bg];
    const s16x8 BH1 = *(const s16x8*)&hBhi[cur][bn][32 + bg];
    const s16x8 BL1 = *(const s16x8*)&hBlo[cur][bn][32 + bg];
    const s16x8 BH2 = *(const s16x8*)&hBhi[cur][bn][64 + bg];
    const s16x8 BL2 = *(const s16x8*)&hBlo[cur][bn][64 + bg];
    const s16x8 BH3 = *(const s16x8*)&hBhi[cur][bn][96 + bg];
    const s16x8 BL3 = *(const s16x8*)&hBlo[cur][bn][96 + bg];
    f32x4 C0 = {0.f,0.f,0.f,0.f};
    f32x4 C1 = {0.f,0.f,0.f,0.f};
    f32x4 C2 = {0.f,0.f,0.f,0.f};
    #define MM(I,KC) \
      C##I = __builtin_amdgcn_mfma_f32_16x16x32_bf16(AL##I##KC, BH##KC, C##I, 0, 0, 0); \
      C##I = __builtin_amdgcn_mfma_f32_16x16x32_bf16(AH##I##KC, BL##KC, C##I, 0, 0, 0); \
      C##I = __builtin_amdgcn_mfma_f32_16x16x32_bf16(AH##I##KC, BH##KC, C##I, 0, 0, 0);
    MM(0,0) MM(1,0) MM(2,0)
    MM(0,1) MM(1,1) MM(2,1)
    MM(0,2) MM(1,2) MM(2,2)
    MM(0,3) MM(1,3) MM(2,3)
    #undef MM
    // C rows: m = (l>>4)*4 + reg (m89-verified); store [gate][chain][row]
    #define SW(I) { const int tt = 3*W + (I); const int rb = ((tt & 7)*16) + ((l >> 4)*4); \
      if (rb < 100) *(f32x4*)&Sg[tt >> 3][l & 15][rb] = C##I; }
    SW(0) SW(1) SW(2)
    #undef SW
    __syncthreads();

    // ---- phase 2: finalize 4 GRU cells per lane (t<400) ----
    if (t < 400){
      const float xc = data[(size_t)(b0 + bcF)*512 + (size_t)(dir ? (511 - s) : s)];
      const f32x4 sr = *(const f32x4*)&Sg[0][bcF][ubc*4];
      const f32x4 sz = *(const f32x4*)&Sg[1][bcF][ubc*4];
      const f32x4 sn = *(const f32x4*)&Sg[2][bcF][ubc*4];
      const f32x4 ho = *(const f32x4*)&hF[bcF][ubc*4];
      f32x4 hn;
      #define FIN(CMP) { \
        const float rr = sigf(sr.CMP + fmaf(wxr4.CMP, xc, bcr4.CMP)); \
        const float zz = sigf(sz.CMP + fmaf(wxz4.CMP, xc, bcz4.CMP)); \
        const float nn = tanhf_fast(fmaf(wxn4.CMP, xc, bxn4.CMP) + rr*(sn.CMP + bhn4.CMP)); \
        hn.CMP = nn + zz*(ho.CMP - nn); }
      FIN(x) FIN(y) FIN(z) FIN(w)
      #undef FIN
      *(f32x4*)&hF[bcF][ubc*4] = hn;
      // bf16 hi/lo into next B buffer
      const unsigned short h0 = f2bf(hn.x), h1 = f2bf(hn.y), h2 = f2bf(hn.z), h3 = f2bf(hn.w);
      uint2 vhi, vlo;
      vhi.x = (unsigned int)h0 | ((unsigned int)h1 << 16);
      vhi.y = (unsigned int)h2 | ((unsigned int)h3 << 16);
      vlo.x = (unsigned int)f2bf(hn.x - bf2f(h0)) | ((unsigned int)f2bf(hn.y - bf2f(h1)) << 16);
      vlo.y = (unsigned int)f2bf(hn.z - bf2f(h2)) | ((unsigned int)f2bf(hn.w - bf2f(h3)) << 16);
      *(uint2*)&hBhi[nxt][bcF][ubc*4] = vhi;
      *(uint2*)&hBlo[nxt][bcF][ubc*4] = vlo;
      if ((s & 3) == 3){
        const int cs = s >> 2;
        const int ch = b0 + bcF;                 // global chain (= batch)
        const size_t base = (((size_t)cs*256 + (ch >> 2))*100);
        x1[(base + ubc*4 + 0)*4 + (ch & 3)] = hn.x;
        x1[(base + ubc*4 + 1)*4 + (ch & 3)] = hn.y;
        x1[(base + ubc*4 + 2)*4 + (ch & 3)] = hn.z;
        x1[(base + ubc*4 + 3)*4 + (ch & 3)] = hn.w;
      }
      if (s == 511){
        const int ch = b0 + bcF;
        *(f32x4*)&out[(size_t)ch*400 + obase + ubc*4] = hn;
      }
    }
    __syncthreads();
  }
}

// ---------------------------------------------------------------------------
// L2: I=100, H=50, 128 steps, lane-3 chains, 4 chains/block, 512 blocks.
// (unchanged from round 4 — verified correct)
// ---------------------------------------------------------------------------
__global__ __launch_bounds__(512, 4)
void gru_l2(const float* __restrict__ x1f, const float* __restrict__ x1b,
            const float* __restrict__ wih_f, const float* __restrict__ whh_f,
            const float* __restrict__ bih_f, const float* __restrict__ bhh_f,
            const float* __restrict__ wih_b, const float* __restrict__ whh_b,
            const float* __restrict__ bih_b, const float* __restrict__ bhh_b,
            float* __restrict__ x2f, float* __restrict__ x2b,
            float* __restrict__ out)
{
  const int dir = (int)(blockIdx.x >> 8);
  const int blk = (int)(blockIdx.x & 255);
  const int t   = (int)threadIdx.x;
  const float* __restrict__ wih = dir ? wih_b : wih_f;
  const float* __restrict__ whh = dir ? whh_b : whh_f;
  const float* __restrict__ bih = dir ? bih_b : bih_f;
  const float* __restrict__ bhh = dir ? bhh_b : bhh_f;
  const float* __restrict__ x1 = dir ? x1b : x1f;
  float* __restrict__ x2 = dir ? x2b : x2f;
  const int obase = dir ? 300 : 100;
  const int b0 = blk * 4;

  __shared__ __align__(16) float xh[2][152][4];

  const int oct = t >> 3;
  const int u   = (oct > 49) ? 49 : oct;
  const int l   = t & 7;
  const int cb  = 19 * l;           // combined col base (0..133)
  float4 W0,W1,W2,W3,W4,W5,W6,W7,W8,W9,W10,W11,W12,W13,W14,W15,W16,W17,W18;
  #define L2LW(J, V) { const int g = cb + (J); \
    const float wr_ = (g<100) ? wih[(size_t)(u     )*100+g] : ((g<150)? whh[(size_t)(u     )*50+g-100] : 0.f); \
    const float wz_ = (g<100) ? wih[(size_t)(u + 50)*100+g] : ((g<150)? whh[(size_t)(u + 50)*50+g-100] : 0.f); \
    const float wx_ = (g<100) ? wih[(size_t)(u +100)*100+g] : 0.f; \
    const float wh_ = (g>=100 && g<150) ? whh[(size_t)(u +100)*50+g-100] : 0.f; \
    V = make_float4(wr_, wz_, wx_, wh_); }
  L2LW(0,W0)  L2LW(1,W1)  L2LW(2,W2)  L2LW(3,W3)  L2LW(4,W4)  L2LW(5,W5)  L2LW(6,W6)
  L2LW(7,W7)  L2LW(8,W8)  L2LW(9,W9)  L2LW(10,W10) L2LW(11,W11) L2LW(12,W12) L2LW(13,W13)
  L2LW(14,W14) L2LW(15,W15) L2LW(16,W16) L2LW(17,W17) L2LW(18,W18)
  #undef L2LW
  const float bcr = bih[u] + bhh[u];
  const float bcz = bih[u+50] + bhh[u+50];
  const float bxn = bih[u+100];
  const float bhn = bhh[u+100];

  for (int i = t; i < 104; i += 512){            // zero h rows + pads, both buffers
    const int bi = (i >= 52) ? 1 : 0;
    const int row = 100 + (i - bi*52);
    *(float4*)&xh[bi][row][0] = make_float4(0.f,0.f,0.f,0.f);
  }
  if (t < 100)                                    // stage x for step 0
    *(float4*)&xh[0][t][0] = *(const float4*)(x1 + (((size_t)0*256 + blk)*100 + t)*4);
  __syncthreads();

  #pragma unroll 1
  for (int s = 0; s < 128; ++s){
    const int cur = s & 1, nxt = cur ^ 1;
    if (t < 400){
      const float* hb = &xh[cur][cb][0];
      float ar0=0,ar1=0,ar2=0,ar3=0, az0=0,az1=0,az2=0,az3=0;
      float ax0=0,ax1=0,ax2=0,ax3=0, ah0=0,ah1=0,ah2=0,ah3=0;
      #define L2C(J, WV) { const float4 h4 = *(const float4*)(hb + 4*(J)); \
        ar0=fmaf(WV.x,h4.x,ar0); ar1=fmaf(WV.x,h4.y,ar1); ar2=fmaf(WV.x,h4.z,ar2); ar3=fmaf(WV.x,h4.w,ar3); \
        az0=fmaf(WV.y,h4.x,az0); az1=fmaf(WV.y,h4.y,az1); az2=fmaf(WV.y,h4.z,az2); az3=fmaf(WV.y,h4.w,az3); \
        ax0=fmaf(WV.z,h4.x,ax0); ax1=fmaf(WV.z,h4.y,ax1); ax2=fmaf(WV.z,h4.z,ax2); ax3=fmaf(WV.z,h4.w,ax3); \
        ah0=fmaf(WV.w,h4.x,ah0); ah1=fmaf(WV.w,h4.y,ah1); ah2=fmaf(WV.w,h4.z,ah2); ah3=fmaf(WV.w,h4.w,ah3); }
      L2C(0,W0)  L2C(1,W1)  L2C(2,W2)  L2C(3,W3)  L2C(4,W4)  L2C(5,W5)  L2C(6,W6)
      L2C(7,W7)  L2C(8,W8)  L2C(9,W9)  L2C(10,W10) L2C(11,W11) L2C(12,W12) L2C(13,W13)
      L2C(14,W14) L2C(15,W15) L2C(16,W16) L2C(17,W17) L2C(18,W18)
      #undef L2C
      ar0=qsum(ar0); ar1=qsum(ar1); ar2=qsum(ar2); ar3=qsum(ar3);
      az0=qsum(az0); az1=qsum(az1); az2=qsum(az2); az3=qsum(az3);
      ax0=qsum(ax0); ax1=qsum(ax1); ax2=qsum(ax2); ax3=qsum(ax3);
      ah0=qsum(ah0); ah1=qsum(ah1); ah2=qsum(ah2); ah3=qsum(ah3);
      ar0=rsum4(ar0); ar1=rsum4(ar1); ar2=rsum4(ar2); ar3=rsum4(ar3);
      az0=rsum4(az0); az1=rsum4(az1); az2=rsum4(az2); az3=rsum4(az3);
      ax0=rsum4(ax0); ax1=rsum4(ax1); ax2=rsum4(ax2); ax3=rsum4(ax3);
      ah0=rsum4(ah0); ah1=rsum4(ah1); ah2=rsum4(ah2); ah3=rsum4(ah3);
      if (l < 4){
        const float Ar = sel4(l, make_float4(ar0,ar1,ar2,ar3));
        const float Az = sel4(l, make_float4(az0,az1,az2,az3));
        const float Ax = sel4(l, make_float4(ax0,ax1,ax2,ax3));
        const float Ah = sel4(l, make_float4(ah0,ah1,ah2,ah3));
        const float ho = xh[cur][100+u][l];
        const float r = sigf(Ar + bcr);
        const float z = sigf(Az + bcz);
        const float n = tanhf_fast(Ax + bxn + r*(Ah + bhn));
        const float hnew = n + z*(ho - n);
        xh[nxt][100+u][l] = hnew;
        if ((s & 3) == 3) x2[(((size_t)(s>>2)*256 + blk)*50 + u)*4 + l] = hnew;
        if (s == 127)     out[(size_t)(b0 + l)*400 + obase + u] = hnew;
      }
    } else if (t < 500){
      if (s + 1 < 128){
        const int j = t - 400;
        *(float4*)&xh[nxt][j][0] = *(const float4*)(x1 + (((size_t)(s+1)*256 + blk)*100 + j)*4);
      }
    }
    __syncthreads();
  }
}

// ---------------------------------------------------------------------------
// L3: I=50, H=50, 32 steps, lane-15 chains. (unchanged from round 4)
// ---------------------------------------------------------------------------
__global__ __launch_bounds__(512, 4)
void gru_l3(const float* __restrict__ x2f, const float* __restrict__ x2b,
            const float* __restrict__ wih_f, const float* __restrict__ whh_f,
            const float* __restrict__ bih_f, const float* __restrict__ bhh_f,
            const float* __restrict__ wih_b, const float* __restrict__ whh_b,
            const float* __restrict__ bih_b, const float* __restrict__ bhh_b,
            float* __restrict__ out)
{
  const int dir = (int)(blockIdx.x >> 8);
  const int blk = (int)(blockIdx.x & 255);
  const int t   = (int)threadIdx.x;
  const float* __restrict__ wih = dir ? wih_b : wih_f;
  const float* __restrict__ whh = dir ? whh_b : whh_f;
  const float* __restrict__ bih = dir ? bih_b : bih_f;
  const float* __restrict__ bhh = dir ? bhh_b : bhh_f;
  const float* __restrict__ x2 = dir ? x2b : x2f;
  const int obase = dir ? 350 : 150;
  const int b0 = blk * 4;

  __shared__ __align__(16) float xh[2][104][4];

  const int oct = t >> 3;
  const int u   = (oct > 49) ? 49 : oct;
  const int l   = t & 7;
  const int cb  = 13 * l;           // 0..91
  float4 W0,W1,W2,W3,W4,W5,W6,W7,W8,W9,W10,W11,W12;
  #define L3LW(J, V) { const int g = cb + (J); \
    const float wr_ = (g<50) ? wih[(size_t)(u     )*50+g] : ((g<100)? whh[(size_t)(u     )*50+g-50] : 0.f); \
    const float wz_ = (g<50) ? wih[(size_t)(u + 50)*50+g] : ((g<100)? whh[(size_t)(u + 50)*50+g-50] : 0.f); \
    const float wx_ = (g<50) ? wih[(size_t)(u +100)*50+g] : 0.f; \
    const float wh_ = (g>=50 && g<100) ? whh[(size_t)(u +100)*50+g-50] : 0.f; \
    V = make_float4(wr_, wz_, wx_, wh_); }
  L3LW(0,W0) L3LW(1,W1) L3LW(2,W2) L3LW(3,W3) L3LW(4,W4) L3LW(5,W5) L3LW(6,W6)
  L3LW(7,W7) L3LW(8,W8) L3LW(9,W9) L3LW(10,W10) L3LW(11,W11) L3LW(12,W12)
  #undef L3LW
  const float bcr = bih[u] + bhh[u];
  const float bcz = bih[u+50] + bhh[u+50];
  const float bxn = bih[u+100];
  const float bhn = bhh[u+100];

  for (int i = t; i < 108; i += 512){            // zero h rows + pads, both buffers
    const int bi = (i >= 54) ? 1 : 0;
    const int row = 50 + (i - bi*54);
    *(float4*)&xh[bi][row][0] = make_float4(0.f,0.f,0.f,0.f);
  }
  if (t < 50)
    *(float4*)&xh[0][t][0] = *(const float4*)(x2 + (((size_t)0*256 + blk)*50 + t)*4);
  __syncthreads();

  #pragma unroll 1
  for (int s = 0; s < 32; ++s){
    const int cur = s & 1, nxt = cur ^ 1;
    if (t < 400){
      const float* hb = &xh[cur][cb][0];
      float ar0=0,ar1=0,ar2=0,ar3=0, az0=0,az1=0,az2=0,az3=0;
      float ax0=0,ax1=0,ax2=0,ax3=0, ah0=0,ah1=0,ah2=0,ah3=0;
      #define L3C(J, WV) { const float4 h4 = *(const float4*)(hb + 4*(J)); \
        ar0=fmaf(WV.x,h4.x,ar0); ar1=fmaf(WV.x,h4.y,ar1); ar2=fmaf(WV.x,h4.z,ar2); ar3=fmaf(WV.x,h4.w,ar3); \
        az0=fmaf(WV.y,h4.x,az0); az1=fmaf(WV.y,h4.y,az1); az2=fmaf(WV.y,h4.z,az2); az3=fmaf(WV.y,h4.w,az3); \
        ax0=fmaf(WV.z,h4.x,ax0); ax1=fmaf(WV.z,h4.y,ax1); ax2=fmaf(WV.z,h4.z,ax2); ax3=fmaf(WV.z,h4.w,ax3); \
        ah0=fmaf(WV.w,h4.x,ah0); ah1=fmaf(WV.w,h4.y,ah1); ah2=fmaf(WV.w,h4.z,ah2); ah3=fmaf(WV.w,h4.w,ah3); }
      L3C(0,W0) L3C(1,W1) L3C(2,W2) L3C(3,W3) L3C(4,W4) L3C(5,W5) L3C(6,W6)
      L3C(7,W7) L3C(8,W8) L3C(9,W9) L3C(10,W10) L3C(11,W11) L3C(12,W12)
      #undef L3C
      ar0=qsum(ar0); ar1=qsum(ar1); ar2=qsum(ar2); ar3=qsum(ar3);
      az0=qsum(az0); az1=qsum(az1); az2=qsum(az2); az3=qsum(az3);
      ax0=qsum(ax0); ax1=qsum(ax1); ax2=qsum(ax2); ax3=qsum(ax3);
      ah0=qsum(ah0); ah1=qsum(ah1); ah2=qsum(ah2); ah3=qsum(ah3);
      ar0=rsum4(ar0); ar1=rsum4(ar1); ar2=rsum4(ar2); ar3=rsum4(ar3);
      az0=rsum4(az0); az1=rsum4(az1); az2=rsum4(az2); az3=rsum4(az3);
      ax0=rsum4(ax0); ax1=rsum4(ax1); ax2=rsum4(ax2); ax3=rsum4(ax3);
      ah0=rsum4(ah0); ah1=rsum4(ah1); ah2=rsum4(ah2); ah3=rsum4(ah3);
      if (l < 4){
        const float Ar = sel4(l, make_float4(ar0,ar1,ar2,ar3));
        const float Az = sel4(l, make_float4(az0,az1,az2,az3));
        const float Ax = sel4(l, make_float4(ax0,ax1,ax2,ax3));
        const float Ah = sel4(l, make_float4(ah0,ah1,ah2,ah3));
        const float ho = xh[cur][50+u][l];
        const float r = sigf(Ar + bcr);
        const float z = sigf(Az + bcz);
        const float n = tanhf_fast(Ax + bxn + r*(Ah + bhn));
        const float hnew = n + z*(ho - n);
        xh[nxt][50+u][l] = hnew;
        if (s == 31) out[(size_t)(b0 + l)*400 + obase + u] = hnew;
      }
    } else if (t < 450){
      if (s + 1 < 32){
        const int j = t - 400;
        *(float4*)&xh[nxt][j][0] = *(const float4*)(x2 + (((size_t)(s+1)*256 + blk)*50 + j)*4);
      }
    }
    __syncthreads();
  }
}

extern "C" void kernel_launch(void* const* d_in, const int* in_sizes, int n_in,
                              void* d_out, int out_size, void* d_ws, size_t ws_size,
                              hipStream_t stream)
{
  const float* data   = (const float*)d_in[0];
  const float* f1_wih = (const float*)d_in[1];
  const float* f1_whh = (const float*)d_in[2];
  const float* f1_bih = (const float*)d_in[3];
  const float* f1_bhh = (const float*)d_in[4];
  const float* f2_wih = (const float*)d_in[5];
  const float* f2_whh = (const float*)d_in[6];
  const float* f2_bih = (const float*)d_in[7];
  const float* f2_bhh = (const float*)d_in[8];
  const float* f3_wih = (const float*)d_in[9];
  const float* f3_whh = (const float*)d_in[10];
  const float* f3_bih = (const float*)d_in[11];
  const float* f3_bhh = (const float*)d_in[12];
  const float* b1_wih = (const float*)d_in[13];
  const float* b1_whh = (const float*)d_in[14];
  const float* b1_bih = (const float*)d_in[15];
  const float* b1_bhh = (const float*)d_in[16];
  const float* b2_wih = (const float*)d_in[17];
  const float* b2_whh = (const float*)d_in[18];
  const float* b2_bih = (const float*)d_in[19];
  const float* b2_bhh = (const float*)d_in[20];
  const float* b3_wih = (const float*)d_in[21];
  const float* b3_whh = (const float*)d_in[22];
  const float* b3_bih = (const float*)d_in[23];
  const float* b3_bhh = (const float*)d_in[24];
  float* out = (float*)d_out;

  const size_t X1N = (size_t)128 * 256 * 100 * 4;  // [cs][blk][unit][chain]
  const size_t X2N = (size_t)32 * 256 * 50 * 4;    // [k2][blk][unit][chain]
  if (ws_size < (2 * X1N + 2 * X2N) * sizeof(float)) return;
  float* wsf = (float*)d_ws;
  float* x1f = wsf;
  float* x1b = wsf + X1N;
  float* x2f = wsf + 2 * X1N;
  float* x2b = wsf + 2 * X1N + X2N;

  gru_l1<<<dim3(128), dim3(512), 0, stream>>>(
      data, f1_wih, f1_whh, f1_bih, f1_bhh,
      b1_wih, b1_whh, b1_bih, b1_bhh, x1f, x1b, out);
  gru_l2<<<dim3(512), dim3(512), 0, stream>>>(
      x1f, x1b, f2_wih, f2_whh, f2_bih, f2_bhh,
      b2_wih, b2_whh, b2_bih, b2_bhh, x2f, x2b, out);
  gru_l3<<<dim3(512), dim3(512), 0, stream>>>(
      x2f, x2b, f3_wih, f3_whh, f3_bih, f3_bhh,
      b3_wih, b3_whh, b3_bih, b3_bhh, out);
}

// Round 7
// 1250.311 us; speedup vs baseline: 1.2978x; 1.0641x over previous
//
#include <hip/hip_runtime.h>
#include <math.h>

typedef short  s16x8 __attribute__((ext_vector_type(8)));   // 8 bf16 bit-patterns (4 VGPRs)
typedef float  f32x4 __attribute__((ext_vector_type(4)));

static __device__ __forceinline__ float sigf(float x){ return 1.0f/(1.0f+__expf(-x)); }
static __device__ __forceinline__ float tanhf_fast(float x){
  float ax=fabsf(x); float e=__expf(-2.0f*ax); float t=(1.0f-e)/(1.0f+e); return copysignf(t,x);
}
static __device__ __forceinline__ unsigned short f2bf(float x){  // RNE f32->bf16 bits
  unsigned int u = __float_as_uint(x);
  unsigned int r = (u + 0x7FFFu + ((u >> 16) & 1u)) >> 16;
  return (unsigned short)r;
}
static __device__ __forceinline__ float bf2f(unsigned short b){
  return __uint_as_float(((unsigned int)b) << 16);
}
// quad/octet reduce helpers (verified r4) — used by L2/L3
static __device__ __forceinline__ float qsum(float v){
  v += __int_as_float(__builtin_amdgcn_mov_dpp(__float_as_int(v),0xB1,0xF,0xF,true));
  v += __int_as_float(__builtin_amdgcn_mov_dpp(__float_as_int(v),0x4E,0xF,0xF,true));
  return v;
}
static __device__ __forceinline__ float rsum4(float v){
  return v + __int_as_float(__builtin_amdgcn_ds_swizzle(__float_as_int(v), 0x101F));
}
static __device__ __forceinline__ float sel4(int c, float4 v){
  float r=v.x; r=(c==1)?v.y:r; r=(c==2)?v.z:r; r=(c==3)?v.w:r; return r;
}

// A-fragment pair (hi/lo split). Flat packed rows: global row r = tile*16+(l&15)
// indexes whh[r][k] directly (r<300 valid). mfma_f32_16x16x32_bf16 A layout:
// lane l holds A[m = l&15][k = (l>>4)*8 + j].
static __device__ __forceinline__ void load_afrag(const float* __restrict__ whh,
                                                  int tile, int l, int kc,
                                                  s16x8& hi, s16x8& lo){
  const int r  = tile*16 + (l & 15);
  const int kb = kc*32 + (l >> 4)*8;
  #pragma unroll
  for (int j = 0; j < 8; ++j){
    const int k = kb + j;
    const float wv = (r < 300 && k < 100) ? whh[(size_t)r*100 + k] : 0.0f;
    const unsigned short hb = f2bf(wv);
    hi[j] = (short)hb;
    lo[j] = (short)f2bf(wv - bf2f(hb));
  }
}

// ---------------------------------------------------------------------------
// L1 (MFMA): I=1, H=100, 512 steps, 16 chains/block, 128 blocks (64 fwd+64
// bwd), 448 threads = 7 waves. Rows packed: 300 gate-rows in 19 tiles of 16.
// Waves 0-3 do MFMA (5,5,5,4 tiles -> one MFMA wave per SIMD); K = 4 chunks
// of 32; 3-term bf16 split. Weights persist in VGPR/AGPR A-frags. h in LDS
// [chain][k] bf16 hi/lo dbuf. Pre-acts via flat Sg[chain][row 0..303];
// 400 lanes finalize 4 cells each, h_prev in registers. 2 barriers/step.
// ---------------------------------------------------------------------------
__global__ __launch_bounds__(448, 1)
void gru_l1(const float* __restrict__ data,
            const float* __restrict__ wih_f, const float* __restrict__ whh_f,
            const float* __restrict__ bih_f, const float* __restrict__ bhh_f,
            const float* __restrict__ wih_b, const float* __restrict__ whh_b,
            const float* __restrict__ bih_b, const float* __restrict__ bhh_b,
            float* __restrict__ x1f, float* __restrict__ x1b,
            float* __restrict__ out)
{
  const int dir   = (int)(blockIdx.x >> 6);
  const int blk16 = (int)(blockIdx.x & 63);
  const int t     = (int)threadIdx.x;
  const float* __restrict__ wih = dir ? wih_b : wih_f;
  const float* __restrict__ whh = dir ? whh_b : whh_f;
  const float* __restrict__ bih = dir ? bih_b : bih_f;
  const float* __restrict__ bhh = dir ? bhh_b : bhh_f;
  float* __restrict__ x1 = dir ? x1b : x1f;
  const int obase = dir ? 200 : 0;
  const int b0 = blk16 * 16;

  __shared__ __align__(16) unsigned short hBhi[2][16][136]; // [buf][chain][k]
  __shared__ __align__(16) unsigned short hBlo[2][16][136];
  __shared__ __align__(16) float Sg[16][308];               // [chain][flat row]

  { unsigned short* ph = (unsigned short*)hBhi;
    unsigned short* pl = (unsigned short*)hBlo;
    for (int i = t; i < 2*16*136; i += 448){ ph[i] = 0; pl[i] = 0; } }

  const int l = t & 63;
  const int W = t >> 6;   // wave 0..6

  // A-fragments: 5 tiles x 4 kc x (hi,lo). tile = W*5+i; invalid -> zeros.
  s16x8 AH00,AH01,AH02,AH03, AH10,AH11,AH12,AH13, AH20,AH21,AH22,AH23,
        AH30,AH31,AH32,AH33, AH40,AH41,AH42,AH43;
  s16x8 AL00,AL01,AL02,AL03, AL10,AL11,AL12,AL13, AL20,AL21,AL22,AL23,
        AL30,AL31,AL32,AL33, AL40,AL41,AL42,AL43;
  #define LDA(I,KC) load_afrag(whh, 5*W + (I), l, (KC), AH##I##KC, AL##I##KC);
  LDA(0,0) LDA(0,1) LDA(0,2) LDA(0,3)
  LDA(1,0) LDA(1,1) LDA(1,2) LDA(1,3)
  LDA(2,0) LDA(2,1) LDA(2,2) LDA(2,3)
  LDA(3,0) LDA(3,1) LDA(3,2) LDA(3,3)
  LDA(4,0) LDA(4,1) LDA(4,2) LDA(4,3)
  #undef LDA

  // finalize constants (lane t<400 owns units ubc*4..+3, chain bcF)
  const int ubc = ((t < 400) ? t : 399) >> 4;   // 0..24
  const int bcF = t & 15;
  const f32x4 wxr4 = *(const f32x4*)&wih[ubc*4];
  const f32x4 wxz4 = *(const f32x4*)&wih[100 + ubc*4];
  const f32x4 wxn4 = *(const f32x4*)&wih[200 + ubc*4];
  const f32x4 bir  = *(const f32x4*)&bih[ubc*4];
  const f32x4 bhr  = *(const f32x4*)&bhh[ubc*4];
  const f32x4 biz  = *(const f32x4*)&bih[100 + ubc*4];
  const f32x4 bhz  = *(const f32x4*)&bhh[100 + ubc*4];
  const f32x4 bxn4 = *(const f32x4*)&bih[200 + ubc*4];
  const f32x4 bhn4 = *(const f32x4*)&bhh[200 + ubc*4];
  const f32x4 bcr4 = bir + bhr;
  const f32x4 bcz4 = biz + bhz;
  f32x4 hprev = {0.f,0.f,0.f,0.f};

  __syncthreads();

  const int bn = l & 15;        // B-frag: n (chain)
  const int bg = (l >> 4)*8;    // B-frag: k offset within chunk

  #pragma unroll 1
  for (int s = 0; s < 512; ++s){
    const int cur = s & 1, nxt = cur ^ 1;

    // prefetch this step's x (consumed after the barrier; hides under MFMA)
    float xc = 0.f;
    if (t < 400) xc = data[(size_t)(b0 + bcF)*512 + (size_t)(dir ? (511 - s) : s)];

    // ---- phase 1: MFMA (waves 0-3 only; one per SIMD) ----
    if (W < 4){
      const s16x8 BH0 = *(const s16x8*)&hBhi[cur][bn][ 0 + bg];
      const s16x8 BL0 = *(const s16x8*)&hBlo[cur][bn][ 0 + bg];
      const s16x8 BH1 = *(const s16x8*)&hBhi[cur][bn][32 + bg];
      const s16x8 BL1 = *(const s16x8*)&hBlo[cur][bn][32 + bg];
      const s16x8 BH2 = *(const s16x8*)&hBhi[cur][bn][64 + bg];
      const s16x8 BL2 = *(const s16x8*)&hBlo[cur][bn][64 + bg];
      const s16x8 BH3 = *(const s16x8*)&hBhi[cur][bn][96 + bg];
      const s16x8 BL3 = *(const s16x8*)&hBlo[cur][bn][96 + bg];
      f32x4 C0 = {0.f,0.f,0.f,0.f};
      f32x4 C1 = {0.f,0.f,0.f,0.f};
      f32x4 C2 = {0.f,0.f,0.f,0.f};
      f32x4 C3 = {0.f,0.f,0.f,0.f};
      f32x4 C4 = {0.f,0.f,0.f,0.f};
      // tile i=4 exists only for W<3 (tile 19 is the dummy slot)
      #define MM1(I,KC) \
        C##I = __builtin_amdgcn_mfma_f32_16x16x32_bf16(AL##I##KC, BH##KC, C##I, 0, 0, 0); \
        C##I = __builtin_amdgcn_mfma_f32_16x16x32_bf16(AH##I##KC, BL##KC, C##I, 0, 0, 0); \
        C##I = __builtin_amdgcn_mfma_f32_16x16x32_bf16(AH##I##KC, BH##KC, C##I, 0, 0, 0);
      MM1(0,0) MM1(1,0) MM1(2,0) MM1(3,0)
      MM1(0,1) MM1(1,1) MM1(2,1) MM1(3,1)
      MM1(0,2) MM1(1,2) MM1(2,2) MM1(3,2)
      MM1(0,3) MM1(1,3) MM1(2,3) MM1(3,3)
      if (W < 3){ MM1(4,0) MM1(4,1) MM1(4,2) MM1(4,3) }
      #undef MM1
      // C rows: m = (l>>4)*4 + reg; flat row rb = tile*16 + m
      #define SW(I) { const int rb = (5*W + (I))*16 + ((l >> 4)*4); \
        *(f32x4*)&Sg[l & 15][rb] = C##I; }
      SW(0) SW(1) SW(2) SW(3)
      if (W < 3){ SW(4) }
      #undef SW
    }
    __syncthreads();

    // ---- phase 2: finalize 4 GRU cells per lane (t<400) ----
    if (t < 400){
      const f32x4 sr = *(const f32x4*)&Sg[bcF][      ubc*4];
      const f32x4 sz = *(const f32x4*)&Sg[bcF][100 + ubc*4];
      const f32x4 sn = *(const f32x4*)&Sg[bcF][200 + ubc*4];
      f32x4 hn;
      #define FIN(CMP) { \
        const float rr = sigf(sr.CMP + fmaf(wxr4.CMP, xc, bcr4.CMP)); \
        const float zz = sigf(sz.CMP + fmaf(wxz4.CMP, xc, bcz4.CMP)); \
        const float nn = tanhf_fast(fmaf(wxn4.CMP, xc, bxn4.CMP) + rr*(sn.CMP + bhn4.CMP)); \
        hn.CMP = nn + zz*(hprev.CMP - nn); }
      FIN(x) FIN(y) FIN(z) FIN(w)
      #undef FIN
      hprev = hn;
      const unsigned short h0 = f2bf(hn.x), h1 = f2bf(hn.y), h2 = f2bf(hn.z), h3 = f2bf(hn.w);
      uint2 vhi, vlo;
      vhi.x = (unsigned int)h0 | ((unsigned int)h1 << 16);
      vhi.y = (unsigned int)h2 | ((unsigned int)h3 << 16);
      vlo.x = (unsigned int)f2bf(hn.x - bf2f(h0)) | ((unsigned int)f2bf(hn.y - bf2f(h1)) << 16);
      vlo.y = (unsigned int)f2bf(hn.z - bf2f(h2)) | ((unsigned int)f2bf(hn.w - bf2f(h3)) << 16);
      *(uint2*)&hBhi[nxt][bcF][ubc*4] = vhi;
      *(uint2*)&hBlo[nxt][bcF][ubc*4] = vlo;
      if ((s & 3) == 3){
        const int cs = s >> 2;
        const int ch = b0 + bcF;
        const size_t base = (((size_t)cs*256 + (ch >> 2))*100);
        x1[(base + ubc*4 + 0)*4 + (ch & 3)] = hn.x;
        x1[(base + ubc*4 + 1)*4 + (ch & 3)] = hn.y;
        x1[(base + ubc*4 + 2)*4 + (ch & 3)] = hn.z;
        x1[(base + ubc*4 + 3)*4 + (ch & 3)] = hn.w;
      }
      if (s == 511){
        const int ch = b0 + bcF;
        *(f32x4*)&out[(size_t)ch*400 + obase + ubc*4] = hn;
      }
    }
    __syncthreads();
  }
}

// ---------------------------------------------------------------------------
// L2: I=100, H=50, 128 steps, lane-3 chains, 4 chains/block, 512 blocks.
// (unchanged — verified correct)
// ---------------------------------------------------------------------------
__global__ __launch_bounds__(512, 4)
void gru_l2(const float* __restrict__ x1f, const float* __restrict__ x1b,
            const float* __restrict__ wih_f, const float* __restrict__ whh_f,
            const float* __restrict__ bih_f, const float* __restrict__ bhh_f,
            const float* __restrict__ wih_b, const float* __restrict__ whh_b,
            const float* __restrict__ bih_b, const float* __restrict__ bhh_b,
            float* __restrict__ x2f, float* __restrict__ x2b,
            float* __restrict__ out)
{
  const int dir = (int)(blockIdx.x >> 8);
  const int blk = (int)(blockIdx.x & 255);
  const int t   = (int)threadIdx.x;
  const float* __restrict__ wih = dir ? wih_b : wih_f;
  const float* __restrict__ whh = dir ? whh_b : whh_f;
  const float* __restrict__ bih = dir ? bih_b : bih_f;
  const float* __restrict__ bhh = dir ? bhh_b : bhh_f;
  const float* __restrict__ x1 = dir ? x1b : x1f;
  float* __restrict__ x2 = dir ? x2b : x2f;
  const int obase = dir ? 300 : 100;
  const int b0 = blk * 4;

  __shared__ __align__(16) float xh[2][152][4];

  const int oct = t >> 3;
  const int u   = (oct > 49) ? 49 : oct;
  const int l   = t & 7;
  const int cb  = 19 * l;           // combined col base (0..133)
  float4 W0,W1,W2,W3,W4,W5,W6,W7,W8,W9,W10,W11,W12,W13,W14,W15,W16,W17,W18;
  #define L2LW(J, V) { const int g = cb + (J); \
    const float wr_ = (g<100) ? wih[(size_t)(u     )*100+g] : ((g<150)? whh[(size_t)(u     )*50+g-100] : 0.f); \
    const float wz_ = (g<100) ? wih[(size_t)(u + 50)*100+g] : ((g<150)? whh[(size_t)(u + 50)*50+g-100] : 0.f); \
    const float wx_ = (g<100) ? wih[(size_t)(u +100)*100+g] : 0.f; \
    const float wh_ = (g>=100 && g<150) ? whh[(size_t)(u +100)*50+g-100] : 0.f; \
    V = make_float4(wr_, wz_, wx_, wh_); }
  L2LW(0,W0)  L2LW(1,W1)  L2LW(2,W2)  L2LW(3,W3)  L2LW(4,W4)  L2LW(5,W5)  L2LW(6,W6)
  L2LW(7,W7)  L2LW(8,W8)  L2LW(9,W9)  L2LW(10,W10) L2LW(11,W11) L2LW(12,W12) L2LW(13,W13)
  L2LW(14,W14) L2LW(15,W15) L2LW(16,W16) L2LW(17,W17) L2LW(18,W18)
  #undef L2LW
  const float bcr = bih[u] + bhh[u];
  const float bcz = bih[u+50] + bhh[u+50];
  const float bxn = bih[u+100];
  const float bhn = bhh[u+100];

  for (int i = t; i < 104; i += 512){            // zero h rows + pads, both buffers
    const int bi = (i >= 52) ? 1 : 0;
    const int row = 100 + (i - bi*52);
    *(float4*)&xh[bi][row][0] = make_float4(0.f,0.f,0.f,0.f);
  }
  if (t < 100)                                    // stage x for step 0
    *(float4*)&xh[0][t][0] = *(const float4*)(x1 + (((size_t)0*256 + blk)*100 + t)*4);
  __syncthreads();

  #pragma unroll 1
  for (int s = 0; s < 128; ++s){
    const int cur = s & 1, nxt = cur ^ 1;
    if (t < 400){
      const float* hb = &xh[cur][cb][0];
      float ar0=0,ar1=0,ar2=0,ar3=0, az0=0,az1=0,az2=0,az3=0;
      float ax0=0,ax1=0,ax2=0,ax3=0, ah0=0,ah1=0,ah2=0,ah3=0;
      #define L2C(J, WV) { const float4 h4 = *(const float4*)(hb + 4*(J)); \
        ar0=fmaf(WV.x,h4.x,ar0); ar1=fmaf(WV.x,h4.y,ar1); ar2=fmaf(WV.x,h4.z,ar2); ar3=fmaf(WV.x,h4.w,ar3); \
        az0=fmaf(WV.y,h4.x,az0); az1=fmaf(WV.y,h4.y,az1); az2=fmaf(WV.y,h4.z,az2); az3=fmaf(WV.y,h4.w,az3); \
        ax0=fmaf(WV.z,h4.x,ax0); ax1=fmaf(WV.z,h4.y,ax1); ax2=fmaf(WV.z,h4.z,ax2); ax3=fmaf(WV.z,h4.w,ax3); \
        ah0=fmaf(WV.w,h4.x,ah0); ah1=fmaf(WV.w,h4.y,ah1); ah2=fmaf(WV.w,h4.z,ah2); ah3=fmaf(WV.w,h4.w,ah3); }
      L2C(0,W0)  L2C(1,W1)  L2C(2,W2)  L2C(3,W3)  L2C(4,W4)  L2C(5,W5)  L2C(6,W6)
      L2C(7,W7)  L2C(8,W8)  L2C(9,W9)  L2C(10,W10) L2C(11,W11) L2C(12,W12) L2C(13,W13)
      L2C(14,W14) L2C(15,W15) L2C(16,W16) L2C(17,W17) L2C(18,W18)
      #undef L2C
      ar0=qsum(ar0); ar1=qsum(ar1); ar2=qsum(ar2); ar3=qsum(ar3);
      az0=qsum(az0); az1=qsum(az1); az2=qsum(az2); az3=qsum(az3);
      ax0=qsum(ax0); ax1=qsum(ax1); ax2=qsum(ax2); ax3=qsum(ax3);
      ah0=qsum(ah0); ah1=qsum(ah1); ah2=qsum(ah2); ah3=qsum(ah3);
      ar0=rsum4(ar0); ar1=rsum4(ar1); ar2=rsum4(ar2); ar3=rsum4(ar3);
      az0=rsum4(az0); az1=rsum4(az1); az2=rsum4(az2); az3=rsum4(az3);
      ax0=rsum4(ax0); ax1=rsum4(ax1); ax2=rsum4(ax2); ax3=rsum4(ax3);
      ah0=rsum4(ah0); ah1=rsum4(ah1); ah2=rsum4(ah2); ah3=rsum4(ah3);
      if (l < 4){
        const float Ar = sel4(l, make_float4(ar0,ar1,ar2,ar3));
        const float Az = sel4(l, make_float4(az0,az1,az2,az3));
        const float Ax = sel4(l, make_float4(ax0,ax1,ax2,ax3));
        const float Ah = sel4(l, make_float4(ah0,ah1,ah2,ah3));
        const float ho = xh[cur][100+u][l];
        const float r = sigf(Ar + bcr);
        const float z = sigf(Az + bcz);
        const float n = tanhf_fast(Ax + bxn + r*(Ah + bhn));
        const float hnew = n + z*(ho - n);
        xh[nxt][100+u][l] = hnew;
        if ((s & 3) == 3) x2[(((size_t)(s>>2)*256 + blk)*50 + u)*4 + l] = hnew;
        if (s == 127)     out[(size_t)(b0 + l)*400 + obase + u] = hnew;
      }
    } else if (t < 500){
      if (s + 1 < 128){
        const int j = t - 400;
        *(float4*)&xh[nxt][j][0] = *(const float4*)(x1 + (((size_t)(s+1)*256 + blk)*100 + j)*4);
      }
    }
    __syncthreads();
  }
}

// ---------------------------------------------------------------------------
// L3: I=50, H=50, 32 steps, lane-15 chains. (unchanged — verified correct)
// ---------------------------------------------------------------------------
__global__ __launch_bounds__(512, 4)
void gru_l3(const float* __restrict__ x2f, const float* __restrict__ x2b,
            const float* __restrict__ wih_f, const float* __restrict__ whh_f,
            const float* __restrict__ bih_f, const float* __restrict__ bhh_f,
            const float* __restrict__ wih_b, const float* __restrict__ whh_b,
            const float* __restrict__ bih_b, const float* __restrict__ bhh_b,
            float* __restrict__ out)
{
  const int dir = (int)(blockIdx.x >> 8);
  const int blk = (int)(blockIdx.x & 255);
  const int t   = (int)threadIdx.x;
  const float* __restrict__ wih = dir ? wih_b : wih_f;
  const float* __restrict__ whh = dir ? whh_b : whh_f;
  const float* __restrict__ bih = dir ? bih_b : bih_f;
  const float* __restrict__ bhh = dir ? bhh_b : bhh_f;
  const float* __restrict__ x2 = dir ? x2b : x2f;
  const int obase = dir ? 350 : 150;
  const int b0 = blk * 4;

  __shared__ __align__(16) float xh[2][104][4];

  const int oct = t >> 3;
  const int u   = (oct > 49) ? 49 : oct;
  const int l   = t & 7;
  const int cb  = 13 * l;           // 0..91
  float4 W0,W1,W2,W3,W4,W5,W6,W7,W8,W9,W10,W11,W12;
  #define L3LW(J, V) { const int g = cb + (J); \
    const float wr_ = (g<50) ? wih[(size_t)(u     )*50+g] : ((g<100)? whh[(size_t)(u     )*50+g-50] : 0.f); \
    const float wz_ = (g<50) ? wih[(size_t)(u + 50)*50+g] : ((g<100)? whh[(size_t)(u + 50)*50+g-50] : 0.f); \
    const float wx_ = (g<50) ? wih[(size_t)(u +100)*50+g] : 0.f; \
    const float wh_ = (g>=50 && g<100) ? whh[(size_t)(u +100)*50+g-50] : 0.f; \
    V = make_float4(wr_, wz_, wx_, wh_); }
  L3LW(0,W0) L3LW(1,W1) L3LW(2,W2) L3LW(3,W3) L3LW(4,W4) L3LW(5,W5) L3LW(6,W6)
  L3LW(7,W7) L3LW(8,W8) L3LW(9,W9) L3LW(10,W10) L3LW(11,W11) L3LW(12,W12)
  #undef L3LW
  const float bcr = bih[u] + bhh[u];
  const float bcz = bih[u+50] + bhh[u+50];
  const float bxn = bih[u+100];
  const float bhn = bhh[u+100];

  for (int i = t; i < 108; i += 512){            // zero h rows + pads, both buffers
    const int bi = (i >= 54) ? 1 : 0;
    const int row = 50 + (i - bi*54);
    *(float4*)&xh[bi][row][0] = make_float4(0.f,0.f,0.f,0.f);
  }
  if (t < 50)
    *(float4*)&xh[0][t][0] = *(const float4*)(x2 + (((size_t)0*256 + blk)*50 + t)*4);
  __syncthreads();

  #pragma unroll 1
  for (int s = 0; s < 32; ++s){
    const int cur = s & 1, nxt = cur ^ 1;
    if (t < 400){
      const float* hb = &xh[cur][cb][0];
      float ar0=0,ar1=0,ar2=0,ar3=0, az0=0,az1=0,az2=0,az3=0;
      float ax0=0,ax1=0,ax2=0,ax3=0, ah0=0,ah1=0,ah2=0,ah3=0;
      #define L3C(J, WV) { const float4 h4 = *(const float4*)(hb + 4*(J)); \
        ar0=fmaf(WV.x,h4.x,ar0); ar1=fmaf(WV.x,h4.y,ar1); ar2=fmaf(WV.x,h4.z,ar2); ar3=fmaf(WV.x,h4.w,ar3); \
        az0=fmaf(WV.y,h4.x,az0); az1=fmaf(WV.y,h4.y,az1); az2=fmaf(WV.y,h4.z,az2); az3=fmaf(WV.y,h4.w,az3); \
        ax0=fmaf(WV.z,h4.x,ax0); ax1=fmaf(WV.z,h4.y,ax1); ax2=fmaf(WV.z,h4.z,ax2); ax3=fmaf(WV.z,h4.w,ax3); \
        ah0=fmaf(WV.w,h4.x,ah0); ah1=fmaf(WV.w,h4.y,ah1); ah2=fmaf(WV.w,h4.z,ah2); ah3=fmaf(WV.w,h4.w,ah3); }
      L3C(0,W0) L3C(1,W1) L3C(2,W2) L3C(3,W3) L3C(4,W4) L3C(5,W5) L3C(6,W6)
      L3C(7,W7) L3C(8,W8) L3C(9,W9) L3C(10,W10) L3C(11,W11) L3C(12,W12)
      #undef L3C
      ar0=qsum(ar0); ar1=qsum(ar1); ar2=qsum(ar2); ar3=qsum(ar3);
      az0=qsum(az0); az1=qsum(az1); az2=qsum(az2); az3=qsum(az3);
      ax0=qsum(ax0); ax1=qsum(ax1); ax2=qsum(ax2); ax3=qsum(ax3);
      ah0=qsum(ah0); ah1=qsum(ah1); ah2=qsum(ah2); ah3=qsum(ah3);
      ar0=rsum4(ar0); ar1=rsum4(ar1); ar2=rsum4(ar2); ar3=rsum4(ar3);
      az0=rsum4(az0); az1=rsum4(az1); az2=rsum4(az2); az3=rsum4(az3);
      ax0=rsum4(ax0); ax1=rsum4(ax1); ax2=rsum4(ax2); ax3=rsum4(ax3);
      ah0=rsum4(ah0); ah1=rsum4(ah1); ah2=rsum4(ah2); ah3=rsum4(ah3);
      if (l < 4){
        const float Ar = sel4(l, make_float4(ar0,ar1,ar2,ar3));
        const float Az = sel4(l, make_float4(az0,az1,az2,az3));
        const float Ax = sel4(l, make_float4(ax0,ax1,ax2,ax3));
        const float Ah = sel4(l, make_float4(ah0,ah1,ah2,ah3));
        const float ho = xh[cur][50+u][l];
        const float r = sigf(Ar + bcr);
        const float z = sigf(Az + bcz);
        const float n = tanhf_fast(Ax + bxn + r*(Ah + bhn));
        const float hnew = n + z*(ho - n);
        xh[nxt][50+u][l] = hnew;
        if (s == 31) out[(size_t)(b0 + l)*400 + obase + u] = hnew;
      }
    } else if (t < 450){
      if (s + 1 < 32){
        const int j = t - 400;
        *(float4*)&xh[nxt][j][0] = *(const float4*)(x2 + (((size_t)(s+1)*256 + blk)*50 + j)*4);
      }
    }
    __syncthreads();
  }
}

extern "C" void kernel_launch(void* const* d_in, const int* in_sizes, int n_in,
                              void* d_out, int out_size, void* d_ws, size_t ws_size,
                              hipStream_t stream)
{
  const float* data   = (const float*)d_in[0];
  const float* f1_wih = (const float*)d_in[1];
  const float* f1_whh = (const float*)d_in[2];
  const float* f1_bih = (const float*)d_in[3];
  const float* f1_bhh = (const float*)d_in[4];
  const float* f2_wih = (const float*)d_in[5];
  const float* f2_whh = (const float*)d_in[6];
  const float* f2_bih = (const float*)d_in[7];
  const float* f2_bhh = (const float*)d_in[8];
  const float* f3_wih = (const float*)d_in[9];
  const float* f3_whh = (const float*)d_in[10];
  const float* f3_bih = (const float*)d_in[11];
  const float* f3_bhh = (const float*)d_in[12];
  const float* b1_wih = (const float*)d_in[13];
  const float* b1_whh = (const float*)d_in[14];
  const float* b1_bih = (const float*)d_in[15];
  const float* b1_bhh = (const float*)d_in[16];
  const float* b2_wih = (const float*)d_in[17];
  const float* b2_whh = (const float*)d_in[18];
  const float* b2_bih = (const float*)d_in[19];
  const float* b2_bhh = (const float*)d_in[20];
  const float* b3_wih = (const float*)d_in[21];
  const float* b3_whh = (const float*)d_in[22];
  const float* b3_bih = (const float*)d_in[23];
  const float* b3_bhh = (const float*)d_in[24];
  float* out = (float*)d_out;

  const size_t X1N = (size_t)128 * 256 * 100 * 4;  // [cs][blk][unit][chain]
  const size_t X2N = (size_t)32 * 256 * 50 * 4;    // [k2][blk][unit][chain]
  if (ws_size < (2 * X1N + 2 * X2N) * sizeof(float)) return;
  float* wsf = (float*)d_ws;
  float* x1f = wsf;
  float* x1b = wsf + X1N;
  float* x2f = wsf + 2 * X1N;
  float* x2b = wsf + 2 * X1N + X2N;

  gru_l1<<<dim3(128), dim3(448), 0, stream>>>(
      data, f1_wih, f1_whh, f1_bih, f1_bhh,
      b1_wih, b1_whh, b1_bih, b1_bhh, x1f, x1b, out);
  gru_l2<<<dim3(512), dim3(512), 0, stream>>>(
      x1f, x1b, f2_wih, f2_whh, f2_bih, f2_bhh,
      b2_wih, b2_whh, b2_bih, b2_bhh, x2f, x2b, out);
  gru_l3<<<dim3(512), dim3(512), 0, stream>>>(
      x2f, x2b, f3_wih, f3_whh, f3_bih, f3_bhh,
      b3_wih, b3_whh, b3_bih, b3_bhh, out);
}

// Round 8
// 1185.177 us; speedup vs baseline: 1.3691x; 1.0550x over previous
//
#include <hip/hip_runtime.h>
#include <math.h>

typedef short  s16x8 __attribute__((ext_vector_type(8)));   // 8 bf16 bit-patterns (4 VGPRs)
typedef float  f32x4 __attribute__((ext_vector_type(4)));

static __device__ __forceinline__ float sigf(float x){ return 1.0f/(1.0f+__expf(-x)); }
static __device__ __forceinline__ float tanhf_fast(float x){
  float ax=fabsf(x); float e=__expf(-2.0f*ax); float t=(1.0f-e)/(1.0f+e); return copysignf(t,x);
}
static __device__ __forceinline__ unsigned short f2bf(float x){  // RNE f32->bf16 bits
  unsigned int u = __float_as_uint(x);
  unsigned int r = (u + 0x7FFFu + ((u >> 16) & 1u)) >> 16;
  return (unsigned short)r;
}
static __device__ __forceinline__ float bf2f(unsigned short b){
  return __uint_as_float(((unsigned int)b) << 16);
}
// quad/octet reduce helpers (verified r4) — used by L2/L3
static __device__ __forceinline__ float qsum(float v){
  v += __int_as_float(__builtin_amdgcn_mov_dpp(__float_as_int(v),0xB1,0xF,0xF,true));
  v += __int_as_float(__builtin_amdgcn_mov_dpp(__float_as_int(v),0x4E,0xF,0xF,true));
  return v;
}
static __device__ __forceinline__ float rsum4(float v){
  return v + __int_as_float(__builtin_amdgcn_ds_swizzle(__float_as_int(v), 0x101F));
}
static __device__ __forceinline__ float sel4(int c, float4 v){
  float r=v.x; r=(c==1)?v.y:r; r=(c==2)?v.z:r; r=(c==3)?v.w:r; return r;
}

// A-fragment pair (hi/lo split), per-gate tiling: wave ti owns rows
// ti*16..ti*16+15 of gate g. mfma_f32_16x16x32_bf16 A layout:
// lane l holds A[m = l&15][k = (l>>4)*8 + j].
static __device__ __forceinline__ void load_afrag(const float* __restrict__ whh,
                                                  int gate, int ti, int l, int kc,
                                                  s16x8& hi, s16x8& lo){
  const int r  = ti*16 + (l & 15);           // row within gate (pad >=100 -> 0)
  const int kb = kc*32 + (l >> 4)*8;
  #pragma unroll
  for (int j = 0; j < 8; ++j){
    const int k = kb + j;
    const float wv = (r < 100 && k < 100) ? whh[(size_t)(gate*100 + r)*100 + k] : 0.0f;
    const unsigned short hb = f2bf(wv);
    hi[j] = (short)hb;
    lo[j] = (short)f2bf(wv - bf2f(hb));
  }
}

// ---------------------------------------------------------------------------
// L1 (MFMA, fused finalize): I=1, H=100, 512 steps, 16 chains/block,
// 128 blocks (64 fwd + 64 bwd), 448 threads = 7 waves. Wave ti owns row-tile
// ti (16 units) of ALL 3 gates => C frags for r,z,n of unit u=ti*16+(l>>4)*4
// +reg, chain l&15 land in the SAME lane/reg. GRU nonlinearity applied
// directly on C fragments in-register; hnew (4 consecutive units x 1 chain)
// packs to one uint2 per hi/lo buffer. ONE barrier/step, no Sg, no phase-2
// waves. x staged to LDS once. Weights persist in VGPR A-frags (3-term
// bf16 split, fp32-grade).
// ---------------------------------------------------------------------------
__global__ __launch_bounds__(448, 2)
void gru_l1(const float* __restrict__ data,
            const float* __restrict__ wih_f, const float* __restrict__ whh_f,
            const float* __restrict__ bih_f, const float* __restrict__ bhh_f,
            const float* __restrict__ wih_b, const float* __restrict__ whh_b,
            const float* __restrict__ bih_b, const float* __restrict__ bhh_b,
            float* __restrict__ x1f, float* __restrict__ x1b,
            float* __restrict__ out)
{
  const int dir   = (int)(blockIdx.x >> 6);
  const int blk16 = (int)(blockIdx.x & 63);
  const int t     = (int)threadIdx.x;
  const float* __restrict__ wih = dir ? wih_b : wih_f;
  const float* __restrict__ whh = dir ? whh_b : whh_f;
  const float* __restrict__ bih = dir ? bih_b : bih_f;
  const float* __restrict__ bhh = dir ? bhh_b : bhh_f;
  float* __restrict__ x1 = dir ? x1b : x1f;
  const int obase = dir ? 200 : 0;
  const int b0 = blk16 * 16;

  __shared__ __align__(16) unsigned short hBhi[2][16][136]; // [buf][chain][k]
  __shared__ __align__(16) unsigned short hBlo[2][16][136];
  __shared__ __align__(16) float xs[512][16];               // [step][chain], dir-adjusted

  // stage x (coalesced: consecutive t -> consecutive s)
  for (int i = t; i < 8192; i += 448){
    const int c  = i >> 9;
    const int sL = i & 511;
    xs[sL][c] = data[(size_t)(b0 + c)*512 + (size_t)(dir ? (511 - sL) : sL)];
  }
  { unsigned short* ph = (unsigned short*)hBhi;
    unsigned short* pl = (unsigned short*)hBlo;
    for (int i = t; i < 2*16*136; i += 448){ ph[i] = 0; pl[i] = 0; } }

  const int l  = t & 63;
  const int W  = t >> 6;   // wave = row-tile ti (0..6)

  // A-fragments: 3 gates x 4 kc x (hi,lo) = 24 frags (96 VGPRs)
  s16x8 AH00,AH01,AH02,AH03, AH10,AH11,AH12,AH13, AH20,AH21,AH22,AH23;
  s16x8 AL00,AL01,AL02,AL03, AL10,AL11,AL12,AL13, AL20,AL21,AL22,AL23;
  #define LDA(G,KC) load_afrag(whh, G, W, l, KC, AH##G##KC, AL##G##KC);
  LDA(0,0) LDA(0,1) LDA(0,2) LDA(0,3)
  LDA(1,0) LDA(1,1) LDA(1,2) LDA(1,3)
  LDA(2,0) LDA(2,1) LDA(2,2) LDA(2,3)
  #undef LDA

  // per-lane finalize constants: units u0..u0+3, chain c
  const int mg  = (l >> 4) * 4;
  const int u0  = W*16 + mg;                 // 0..124 (multiple of 4)
  const bool uvalid = (u0 < 100);
  const int u0c = uvalid ? u0 : 96;          // clamp for safe loads
  const int c   = l & 15;
  const f32x4 wxr4 = *(const f32x4*)&wih[u0c];
  const f32x4 wxz4 = *(const f32x4*)&wih[100 + u0c];
  const f32x4 wxn4 = *(const f32x4*)&wih[200 + u0c];
  const f32x4 bcr4 = *(const f32x4*)&bih[u0c]       + *(const f32x4*)&bhh[u0c];
  const f32x4 bcz4 = *(const f32x4*)&bih[100 + u0c] + *(const f32x4*)&bhh[100 + u0c];
  const f32x4 bxn4 = *(const f32x4*)&bih[200 + u0c];
  const f32x4 bhn4 = *(const f32x4*)&bhh[200 + u0c];
  f32x4 hprev = {0.f,0.f,0.f,0.f};

  __syncthreads();

  const int bn = l & 15;        // B-frag: chain
  const int bg = (l >> 4)*8;    // B-frag: k offset within chunk

  #pragma unroll 1
  for (int s = 0; s < 512; ++s){
    const int cur = s & 1, nxt = cur ^ 1;

    // ---- B fragments (shared h, bf16 hi/lo) ----
    const s16x8 BH0 = *(const s16x8*)&hBhi[cur][bn][ 0 + bg];
    const s16x8 BL0 = *(const s16x8*)&hBlo[cur][bn][ 0 + bg];
    const s16x8 BH1 = *(const s16x8*)&hBhi[cur][bn][32 + bg];
    const s16x8 BL1 = *(const s16x8*)&hBlo[cur][bn][32 + bg];
    const s16x8 BH2 = *(const s16x8*)&hBhi[cur][bn][64 + bg];
    const s16x8 BL2 = *(const s16x8*)&hBlo[cur][bn][64 + bg];
    const s16x8 BH3 = *(const s16x8*)&hBhi[cur][bn][96 + bg];
    const s16x8 BL3 = *(const s16x8*)&hBlo[cur][bn][96 + bg];

    // ---- MFMA: 3 gates, 2 accumulators each (halve chain depth) ----
    f32x4 Ca0={0.f,0.f,0.f,0.f}, Cb0={0.f,0.f,0.f,0.f};
    f32x4 Ca1={0.f,0.f,0.f,0.f}, Cb1={0.f,0.f,0.f,0.f};
    f32x4 Ca2={0.f,0.f,0.f,0.f}, Cb2={0.f,0.f,0.f,0.f};
    #define MM(ACC,G,KC) \
      ACC = __builtin_amdgcn_mfma_f32_16x16x32_bf16(AL##G##KC, BH##KC, ACC, 0, 0, 0); \
      ACC = __builtin_amdgcn_mfma_f32_16x16x32_bf16(AH##G##KC, BL##KC, ACC, 0, 0, 0); \
      ACC = __builtin_amdgcn_mfma_f32_16x16x32_bf16(AH##G##KC, BH##KC, ACC, 0, 0, 0);
    MM(Ca0,0,0) MM(Ca1,1,0) MM(Ca2,2,0)
    MM(Cb0,0,2) MM(Cb1,1,2) MM(Cb2,2,2)
    MM(Ca0,0,1) MM(Ca1,1,1) MM(Ca2,2,1)
    MM(Cb0,0,3) MM(Cb1,1,3) MM(Cb2,2,3)
    #undef MM
    const f32x4 sr = Ca0 + Cb0;
    const f32x4 sz = Ca1 + Cb1;
    const f32x4 sn = Ca2 + Cb2;

    // ---- fused finalize (lane-local: same lane holds r,z,n for its units) ----
    const float xc = xs[s][c];
    f32x4 hn;
    #define FIN(I) { \
      const float rr = sigf(sr[I] + fmaf(wxr4[I], xc, bcr4[I])); \
      const float zz = sigf(sz[I] + fmaf(wxz4[I], xc, bcz4[I])); \
      const float nn = tanhf_fast(fmaf(wxn4[I], xc, bxn4[I]) + rr*(sn[I] + bhn4[I])); \
      hn[I] = nn + zz*(hprev[I] - nn); }
    FIN(0) FIN(1) FIN(2) FIN(3)
    #undef FIN
    hprev = hn;

    if (uvalid){
      const unsigned short h0 = f2bf(hn[0]), h1 = f2bf(hn[1]), h2 = f2bf(hn[2]), h3 = f2bf(hn[3]);
      uint2 vhi, vlo;
      vhi.x = (unsigned int)h0 | ((unsigned int)h1 << 16);
      vhi.y = (unsigned int)h2 | ((unsigned int)h3 << 16);
      vlo.x = (unsigned int)f2bf(hn[0] - bf2f(h0)) | ((unsigned int)f2bf(hn[1] - bf2f(h1)) << 16);
      vlo.y = (unsigned int)f2bf(hn[2] - bf2f(h2)) | ((unsigned int)f2bf(hn[3] - bf2f(h3)) << 16);
      *(uint2*)&hBhi[nxt][c][u0] = vhi;
      *(uint2*)&hBlo[nxt][c][u0] = vlo;
      if ((s & 3) == 3){
        const int cs = s >> 2;
        const int ch = b0 + c;
        const size_t base = (((size_t)cs*256 + (ch >> 2))*100);
        x1[(base + u0 + 0)*4 + (ch & 3)] = hn[0];
        x1[(base + u0 + 1)*4 + (ch & 3)] = hn[1];
        x1[(base + u0 + 2)*4 + (ch & 3)] = hn[2];
        x1[(base + u0 + 3)*4 + (ch & 3)] = hn[3];
      }
      if (s == 511){
        const int ch = b0 + c;
        *(f32x4*)&out[(size_t)ch*400 + obase + u0] = hn;
      }
    }
    __syncthreads();
  }
}

// ---------------------------------------------------------------------------
// L2: I=100, H=50, 128 steps, lane-3 chains, 4 chains/block, 512 blocks.
// (unchanged — verified correct)
// ---------------------------------------------------------------------------
__global__ __launch_bounds__(512, 4)
void gru_l2(const float* __restrict__ x1f, const float* __restrict__ x1b,
            const float* __restrict__ wih_f, const float* __restrict__ whh_f,
            const float* __restrict__ bih_f, const float* __restrict__ bhh_f,
            const float* __restrict__ wih_b, const float* __restrict__ whh_b,
            const float* __restrict__ bih_b, const float* __restrict__ bhh_b,
            float* __restrict__ x2f, float* __restrict__ x2b,
            float* __restrict__ out)
{
  const int dir = (int)(blockIdx.x >> 8);
  const int blk = (int)(blockIdx.x & 255);
  const int t   = (int)threadIdx.x;
  const float* __restrict__ wih = dir ? wih_b : wih_f;
  const float* __restrict__ whh = dir ? whh_b : whh_f;
  const float* __restrict__ bih = dir ? bih_b : bih_f;
  const float* __restrict__ bhh = dir ? bhh_b : bhh_f;
  const float* __restrict__ x1 = dir ? x1b : x1f;
  float* __restrict__ x2 = dir ? x2b : x2f;
  const int obase = dir ? 300 : 100;
  const int b0 = blk * 4;

  __shared__ __align__(16) float xh[2][152][4];

  const int oct = t >> 3;
  const int u   = (oct > 49) ? 49 : oct;
  const int l   = t & 7;
  const int cb  = 19 * l;           // combined col base (0..133)
  float4 W0,W1,W2,W3,W4,W5,W6,W7,W8,W9,W10,W11,W12,W13,W14,W15,W16,W17,W18;
  #define L2LW(J, V) { const int g = cb + (J); \
    const float wr_ = (g<100) ? wih[(size_t)(u     )*100+g] : ((g<150)? whh[(size_t)(u     )*50+g-100] : 0.f); \
    const float wz_ = (g<100) ? wih[(size_t)(u + 50)*100+g] : ((g<150)? whh[(size_t)(u + 50)*50+g-100] : 0.f); \
    const float wx_ = (g<100) ? wih[(size_t)(u +100)*100+g] : 0.f; \
    const float wh_ = (g>=100 && g<150) ? whh[(size_t)(u +100)*50+g-100] : 0.f; \
    V = make_float4(wr_, wz_, wx_, wh_); }
  L2LW(0,W0)  L2LW(1,W1)  L2LW(2,W2)  L2LW(3,W3)  L2LW(4,W4)  L2LW(5,W5)  L2LW(6,W6)
  L2LW(7,W7)  L2LW(8,W8)  L2LW(9,W9)  L2LW(10,W10) L2LW(11,W11) L2LW(12,W12) L2LW(13,W13)
  L2LW(14,W14) L2LW(15,W15) L2LW(16,W16) L2LW(17,W17) L2LW(18,W18)
  #undef L2LW
  const float bcr = bih[u] + bhh[u];
  const float bcz = bih[u+50] + bhh[u+50];
  const float bxn = bih[u+100];
  const float bhn = bhh[u+100];

  for (int i = t; i < 104; i += 512){            // zero h rows + pads, both buffers
    const int bi = (i >= 52) ? 1 : 0;
    const int row = 100 + (i - bi*52);
    *(float4*)&xh[bi][row][0] = make_float4(0.f,0.f,0.f,0.f);
  }
  if (t < 100)                                    // stage x for step 0
    *(float4*)&xh[0][t][0] = *(const float4*)(x1 + (((size_t)0*256 + blk)*100 + t)*4);
  __syncthreads();

  #pragma unroll 1
  for (int s = 0; s < 128; ++s){
    const int cur = s & 1, nxt = cur ^ 1;
    if (t < 400){
      const float* hb = &xh[cur][cb][0];
      float ar0=0,ar1=0,ar2=0,ar3=0, az0=0,az1=0,az2=0,az3=0;
      float ax0=0,ax1=0,ax2=0,ax3=0, ah0=0,ah1=0,ah2=0,ah3=0;
      #define L2C(J, WV) { const float4 h4 = *(const float4*)(hb + 4*(J)); \
        ar0=fmaf(WV.x,h4.x,ar0); ar1=fmaf(WV.x,h4.y,ar1); ar2=fmaf(WV.x,h4.z,ar2); ar3=fmaf(WV.x,h4.w,ar3); \
        az0=fmaf(WV.y,h4.x,az0); az1=fmaf(WV.y,h4.y,az1); az2=fmaf(WV.y,h4.z,az2); az3=fmaf(WV.y,h4.w,az3); \
        ax0=fmaf(WV.z,h4.x,ax0); ax1=fmaf(WV.z,h4.y,ax1); ax2=fmaf(WV.z,h4.z,ax2); ax3=fmaf(WV.z,h4.w,ax3); \
        ah0=fmaf(WV.w,h4.x,ah0); ah1=fmaf(WV.w,h4.y,ah1); ah2=fmaf(WV.w,h4.z,ah2); ah3=fmaf(WV.w,h4.w,ah3); }
      L2C(0,W0)  L2C(1,W1)  L2C(2,W2)  L2C(3,W3)  L2C(4,W4)  L2C(5,W5)  L2C(6,W6)
      L2C(7,W7)  L2C(8,W8)  L2C(9,W9)  L2C(10,W10) L2C(11,W11) L2C(12,W12) L2C(13,W13)
      L2C(14,W14) L2C(15,W15) L2C(16,W16) L2C(17,W17) L2C(18,W18)
      #undef L2C
      ar0=qsum(ar0); ar1=qsum(ar1); ar2=qsum(ar2); ar3=qsum(ar3);
      az0=qsum(az0); az1=qsum(az1); az2=qsum(az2); az3=qsum(az3);
      ax0=qsum(ax0); ax1=qsum(ax1); ax2=qsum(ax2); ax3=qsum(ax3);
      ah0=qsum(ah0); ah1=qsum(ah1); ah2=qsum(ah2); ah3=qsum(ah3);
      ar0=rsum4(ar0); ar1=rsum4(ar1); ar2=rsum4(ar2); ar3=rsum4(ar3);
      az0=rsum4(az0); az1=rsum4(az1); az2=rsum4(az2); az3=rsum4(az3);
      ax0=rsum4(ax0); ax1=rsum4(ax1); ax2=rsum4(ax2); ax3=rsum4(ax3);
      ah0=rsum4(ah0); ah1=rsum4(ah1); ah2=rsum4(ah2); ah3=rsum4(ah3);
      if (l < 4){
        const float Ar = sel4(l, make_float4(ar0,ar1,ar2,ar3));
        const float Az = sel4(l, make_float4(az0,az1,az2,az3));
        const float Ax = sel4(l, make_float4(ax0,ax1,ax2,ax3));
        const float Ah = sel4(l, make_float4(ah0,ah1,ah2,ah3));
        const float ho = xh[cur][100+u][l];
        const float r = sigf(Ar + bcr);
        const float z = sigf(Az + bcz);
        const float n = tanhf_fast(Ax + bxn + r*(Ah + bhn));
        const float hnew = n + z*(ho - n);
        xh[nxt][100+u][l] = hnew;
        if ((s & 3) == 3) x2[(((size_t)(s>>2)*256 + blk)*50 + u)*4 + l] = hnew;
        if (s == 127)     out[(size_t)(b0 + l)*400 + obase + u] = hnew;
      }
    } else if (t < 500){
      if (s + 1 < 128){
        const int j = t - 400;
        *(float4*)&xh[nxt][j][0] = *(const float4*)(x1 + (((size_t)(s+1)*256 + blk)*100 + j)*4);
      }
    }
    __syncthreads();
  }
}

// ---------------------------------------------------------------------------
// L3: I=50, H=50, 32 steps, lane-15 chains. (unchanged — verified correct)
// ---------------------------------------------------------------------------
__global__ __launch_bounds__(512, 4)
void gru_l3(const float* __restrict__ x2f, const float* __restrict__ x2b,
            const float* __restrict__ wih_f, const float* __restrict__ whh_f,
            const float* __restrict__ bih_f, const float* __restrict__ bhh_f,
            const float* __restrict__ wih_b, const float* __restrict__ whh_b,
            const float* __restrict__ bih_b, const float* __restrict__ bhh_b,
            float* __restrict__ out)
{
  const int dir = (int)(blockIdx.x >> 8);
  const int blk = (int)(blockIdx.x & 255);
  const int t   = (int)threadIdx.x;
  const float* __restrict__ wih = dir ? wih_b : wih_f;
  const float* __restrict__ whh = dir ? whh_b : whh_f;
  const float* __restrict__ bih = dir ? bih_b : bih_f;
  const float* __restrict__ bhh = dir ? bhh_b : bhh_f;
  const float* __restrict__ x2 = dir ? x2b : x2f;
  const int obase = dir ? 350 : 150;
  const int b0 = blk * 4;

  __shared__ __align__(16) float xh[2][104][4];

  const int oct = t >> 3;
  const int u   = (oct > 49) ? 49 : oct;
  const int l   = t & 7;
  const int cb  = 13 * l;           // 0..91
  float4 W0,W1,W2,W3,W4,W5,W6,W7,W8,W9,W10,W11,W12;
  #define L3LW(J, V) { const int g = cb + (J); \
    const float wr_ = (g<50) ? wih[(size_t)(u     )*50+g] : ((g<100)? whh[(size_t)(u     )*50+g-50] : 0.f); \
    const float wz_ = (g<50) ? wih[(size_t)(u + 50)*50+g] : ((g<100)? whh[(size_t)(u + 50)*50+g-50] : 0.f); \
    const float wx_ = (g<50) ? wih[(size_t)(u +100)*50+g] : 0.f; \
    const float wh_ = (g>=50 && g<100) ? whh[(size_t)(u +100)*50+g-50] : 0.f; \
    V = make_float4(wr_, wz_, wx_, wh_); }
  L3LW(0,W0) L3LW(1,W1) L3LW(2,W2) L3LW(3,W3) L3LW(4,W4) L3LW(5,W5) L3LW(6,W6)
  L3LW(7,W7) L3LW(8,W8) L3LW(9,W9) L3LW(10,W10) L3LW(11,W11) L3LW(12,W12)
  #undef L3LW
  const float bcr = bih[u] + bhh[u];
  const float bcz = bih[u+50] + bhh[u+50];
  const float bxn = bih[u+100];
  const float bhn = bhh[u+100];

  for (int i = t; i < 108; i += 512){            // zero h rows + pads, both buffers
    const int bi = (i >= 54) ? 1 : 0;
    const int row = 50 + (i - bi*54);
    *(float4*)&xh[bi][row][0] = make_float4(0.f,0.f,0.f,0.f);
  }
  if (t < 50)
    *(float4*)&xh[0][t][0] = *(const float4*)(x2 + (((size_t)0*256 + blk)*50 + t)*4);
  __syncthreads();

  #pragma unroll 1
  for (int s = 0; s < 32; ++s){
    const int cur = s & 1, nxt = cur ^ 1;
    if (t < 400){
      const float* hb = &xh[cur][cb][0];
      float ar0=0,ar1=0,ar2=0,ar3=0, az0=0,az1=0,az2=0,az3=0;
      float ax0=0,ax1=0,ax2=0,ax3=0, ah0=0,ah1=0,ah2=0,ah3=0;
      #define L3C(J, WV) { const float4 h4 = *(const float4*)(hb + 4*(J)); \
        ar0=fmaf(WV.x,h4.x,ar0); ar1=fmaf(WV.x,h4.y,ar1); ar2=fmaf(WV.x,h4.z,ar2); ar3=fmaf(WV.x,h4.w,ar3); \
        az0=fmaf(WV.y,h4.x,az0); az1=fmaf(WV.y,h4.y,az1); az2=fmaf(WV.y,h4.z,az2); az3=fmaf(WV.y,h4.w,az3); \
        ax0=fmaf(WV.z,h4.x,ax0); ax1=fmaf(WV.z,h4.y,ax1); ax2=fmaf(WV.z,h4.z,ax2); ax3=fmaf(WV.z,h4.w,ax3); \
        ah0=fmaf(WV.w,h4.x,ah0); ah1=fmaf(WV.w,h4.y,ah1); ah2=fmaf(WV.w,h4.z,ah2); ah3=fmaf(WV.w,h4.w,ah3); }
      L3C(0,W0) L3C(1,W1) L3C(2,W2) L3C(3,W3) L3C(4,W4) L3C(5,W5) L3C(6,W6)
      L3C(7,W7) L3C(8,W8) L3C(9,W9) L3C(10,W10) L3C(11,W11) L3C(12,W12)
      #undef L3C
      ar0=qsum(ar0); ar1=qsum(ar1); ar2=qsum(ar2); ar3=qsum(ar3);
      az0=qsum(az0); az1=qsum(az1); az2=qsum(az2); az3=qsum(az3);
      ax0=qsum(ax0); ax1=qsum(ax1); ax2=qsum(ax2); ax3=qsum(ax3);
      ah0=qsum(ah0); ah1=qsum(ah1); ah2=qsum(ah2); ah3=qsum(ah3);
      ar0=rsum4(ar0); ar1=rsum4(ar1); ar2=rsum4(ar2); ar3=rsum4(ar3);
      az0=rsum4(az0); az1=rsum4(az1); az2=rsum4(az2); az3=rsum4(az3);
      ax0=rsum4(ax0); ax1=rsum4(ax1); ax2=rsum4(ax2); ax3=rsum4(ax3);
      ah0=rsum4(ah0); ah1=rsum4(ah1); ah2=rsum4(ah2); ah3=rsum4(ah3);
      if (l < 4){
        const float Ar = sel4(l, make_float4(ar0,ar1,ar2,ar3));
        const float Az = sel4(l, make_float4(az0,az1,az2,az3));
        const float Ax = sel4(l, make_float4(ax0,ax1,ax2,ax3));
        const float Ah = sel4(l, make_float4(ah0,ah1,ah2,ah3));
        const float ho = xh[cur][50+u][l];
        const float r = sigf(Ar + bcr);
        const float z = sigf(Az + bcz);
        const float n = tanhf_fast(Ax + bxn + r*(Ah + bhn));
        const float hnew = n + z*(ho - n);
        xh[nxt][50+u][l] = hnew;
        if (s == 31) out[(size_t)(b0 + l)*400 + obase + u] = hnew;
      }
    } else if (t < 450){
      if (s + 1 < 32){
        const int j = t - 400;
        *(float4*)&xh[nxt][j][0] = *(const float4*)(x2 + (((size_t)(s+1)*256 + blk)*50 + j)*4);
      }
    }
    __syncthreads();
  }
}

extern "C" void kernel_launch(void* const* d_in, const int* in_sizes, int n_in,
                              void* d_out, int out_size, void* d_ws, size_t ws_size,
                              hipStream_t stream)
{
  const float* data   = (const float*)d_in[0];
  const float* f1_wih = (const float*)d_in[1];
  const float* f1_whh = (const float*)d_in[2];
  const float* f1_bih = (const float*)d_in[3];
  const float* f1_bhh = (const float*)d_in[4];
  const float* f2_wih = (const float*)d_in[5];
  const float* f2_whh = (const float*)d_in[6];
  const float* f2_bih = (const float*)d_in[7];
  const float* f2_bhh = (const float*)d_in[8];
  const float* f3_wih = (const float*)d_in[9];
  const float* f3_whh = (const float*)d_in[10];
  const float* f3_bih = (const float*)d_in[11];
  const float* f3_bhh = (const float*)d_in[12];
  const float* b1_wih = (const float*)d_in[13];
  const float* b1_whh = (const float*)d_in[14];
  const float* b1_bih = (const float*)d_in[15];
  const float* b1_bhh = (const float*)d_in[16];
  const float* b2_wih = (const float*)d_in[17];
  const float* b2_whh = (const float*)d_in[18];
  const float* b2_bih = (const float*)d_in[19];
  const float* b2_bhh = (const float*)d_in[20];
  const float* b3_wih = (const float*)d_in[21];
  const float* b3_whh = (const float*)d_in[22];
  const float* b3_bih = (const float*)d_in[23];
  const float* b3_bhh = (const float*)d_in[24];
  float* out = (float*)d_out;

  const size_t X1N = (size_t)128 * 256 * 100 * 4;  // [cs][blk][unit][chain]
  const size_t X2N = (size_t)32 * 256 * 50 * 4;    // [k2][blk][unit][chain]
  if (ws_size < (2 * X1N + 2 * X2N) * sizeof(float)) return;
  float* wsf = (float*)d_ws;
  float* x1f = wsf;
  float* x1b = wsf + X1N;
  float* x2f = wsf + 2 * X1N;
  float* x2b = wsf + 2 * X1N + X2N;

  gru_l1<<<dim3(128), dim3(448), 0, stream>>>(
      data, f1_wih, f1_whh, f1_bih, f1_bhh,
      b1_wih, b1_whh, b1_bih, b1_bhh, x1f, x1b, out);
  gru_l2<<<dim3(512), dim3(512), 0, stream>>>(
      x1f, x1b, f2_wih, f2_whh, f2_bih, f2_bhh,
      b2_wih, b2_whh, b2_bih, b2_bhh, x2f, x2b, out);
  gru_l3<<<dim3(512), dim3(512), 0, stream>>>(
      x2f, x2b, f3_wih, f3_whh, f3_bih, f3_bhh,
      b3_wih, b3_whh, b3_bih, b3_bhh, out);
}